// Round 1
// baseline (2147.628 us; speedup 1.0000x reference)
//
#include <hip/hip_runtime.h>

#define HID 16

// ---------------------------------------------------------------------------
// conv1 edge pass: m = [x[src](4) | x[dst](4) | ea(8)]  (16)
//   h1 = relu(m @ w1 + b1)   (16x16)
//   h2 = relu(h1 @ w2 + b2)  (16x16)
//   atomicMax(agg[src][j], h2[j])   -- h2 >= 0 so uint-bit max is exact
// ---------------------------------------------------------------------------
__global__ __launch_bounds__(256) void conv1_edges(
    const float* __restrict__ x,    // [N,4]
    const int*   __restrict__ ei,   // [2,E]
    const float* __restrict__ ea,   // [E,8]
    const float* __restrict__ w1,   // [16,16]
    const float* __restrict__ b1,   // [16]
    const float* __restrict__ w2,   // [16,16]
    const float* __restrict__ b2,   // [16]
    unsigned int* __restrict__ agg, // [N,16] float bits
    int E)
{
    int e = blockIdx.x * blockDim.x + threadIdx.x;
    if (e >= E) return;
    int src = ei[e];
    int dst = ei[E + e];

    float m[16];
    {
        float4 xs = *(const float4*)(x + (size_t)src * 4);
        float4 xd = *(const float4*)(x + (size_t)dst * 4);
        m[0] = xs.x; m[1] = xs.y; m[2] = xs.z; m[3] = xs.w;
        m[4] = xd.x; m[5] = xd.y; m[6] = xd.z; m[7] = xd.w;
        float4 a0 = *(const float4*)(ea + (size_t)e * 8);
        float4 a1 = *(const float4*)(ea + (size_t)e * 8 + 4);
        m[8]  = a0.x; m[9]  = a0.y; m[10] = a0.z; m[11] = a0.w;
        m[12] = a1.x; m[13] = a1.y; m[14] = a1.z; m[15] = a1.w;
    }

    float h[16];
    #pragma unroll
    for (int j = 0; j < 16; ++j) h[j] = b1[j];
    #pragma unroll
    for (int k = 0; k < 16; ++k) {
        float mk = m[k];
        #pragma unroll
        for (int j = 0; j < 16; ++j) h[j] = fmaf(mk, w1[k * 16 + j], h[j]);
    }
    #pragma unroll
    for (int j = 0; j < 16; ++j) h[j] = fmaxf(h[j], 0.0f);

    float o[16];
    #pragma unroll
    for (int j = 0; j < 16; ++j) o[j] = b2[j];
    #pragma unroll
    for (int k = 0; k < 16; ++k) {
        float hk = h[k];
        #pragma unroll
        for (int j = 0; j < 16; ++j) o[j] = fmaf(hk, w2[k * 16 + j], o[j]);
    }

    unsigned int* dstp = agg + (size_t)src * 16;
    #pragma unroll
    for (int j = 0; j < 16; ++j) {
        float v = fmaxf(o[j], 0.0f);
        atomicMax(dstp + j, __float_as_uint(v));
    }
}

// ---------------------------------------------------------------------------
// conv2 edge pass: m = [h[src](16) | h[dst](16) | ea(8)]  (40)
//   h1 = relu(m @ w1 + b1)   (40x16)
//   h2 = relu(h1 @ w2 + b2)  (16x16)
//   atomicMax(agg2[src][j], h2[j])
// ---------------------------------------------------------------------------
__global__ __launch_bounds__(256) void conv2_edges(
    const float* __restrict__ h,    // [N,16]  (agg1, already >= 0)
    const int*   __restrict__ ei,   // [2,E]
    const float* __restrict__ ea,   // [E,8]
    const float* __restrict__ w1,   // [40,16]
    const float* __restrict__ b1,   // [16]
    const float* __restrict__ w2,   // [16,16]
    const float* __restrict__ b2,   // [16]
    unsigned int* __restrict__ agg, // [N,16] float bits
    int E)
{
    int e = blockIdx.x * blockDim.x + threadIdx.x;
    if (e >= E) return;
    int src = ei[e];
    int dst = ei[E + e];

    float m[40];
    #pragma unroll
    for (int q = 0; q < 4; ++q) {
        float4 v = *(const float4*)(h + (size_t)src * 16 + q * 4);
        m[q * 4 + 0] = v.x; m[q * 4 + 1] = v.y; m[q * 4 + 2] = v.z; m[q * 4 + 3] = v.w;
    }
    #pragma unroll
    for (int q = 0; q < 4; ++q) {
        float4 v = *(const float4*)(h + (size_t)dst * 16 + q * 4);
        m[16 + q * 4 + 0] = v.x; m[16 + q * 4 + 1] = v.y; m[16 + q * 4 + 2] = v.z; m[16 + q * 4 + 3] = v.w;
    }
    {
        float4 a0 = *(const float4*)(ea + (size_t)e * 8);
        float4 a1 = *(const float4*)(ea + (size_t)e * 8 + 4);
        m[32] = a0.x; m[33] = a0.y; m[34] = a0.z; m[35] = a0.w;
        m[36] = a1.x; m[37] = a1.y; m[38] = a1.z; m[39] = a1.w;
    }

    float t[16];
    #pragma unroll
    for (int j = 0; j < 16; ++j) t[j] = b1[j];
    #pragma unroll
    for (int k = 0; k < 40; ++k) {
        float mk = m[k];
        #pragma unroll
        for (int j = 0; j < 16; ++j) t[j] = fmaf(mk, w1[k * 16 + j], t[j]);
    }
    #pragma unroll
    for (int j = 0; j < 16; ++j) t[j] = fmaxf(t[j], 0.0f);

    float o[16];
    #pragma unroll
    for (int j = 0; j < 16; ++j) o[j] = b2[j];
    #pragma unroll
    for (int k = 0; k < 16; ++k) {
        float tk = t[k];
        #pragma unroll
        for (int j = 0; j < 16; ++j) o[j] = fmaf(tk, w2[k * 16 + j], o[j]);
    }

    unsigned int* dstp = agg + (size_t)src * 16;
    #pragma unroll
    for (int j = 0; j < 16; ++j) {
        float v = fmaxf(o[j], 0.0f);
        atomicMax(dstp + j, __float_as_uint(v));
    }
}

// ---------------------------------------------------------------------------
// head: out[n] = relu(h @ l1_w + l1_b) @ l2_w + l2_b
// ---------------------------------------------------------------------------
__global__ __launch_bounds__(256) void node_head(
    const float* __restrict__ h,     // [N,16]  (agg2)
    const float* __restrict__ l1w,   // [16,16]
    const float* __restrict__ l1b,   // [16]
    const float* __restrict__ l2w,   // [16,1]
    const float* __restrict__ l2b,   // [1]
    float* __restrict__ out,         // [N,1]
    int N)
{
    int n = blockIdx.x * blockDim.x + threadIdx.x;
    if (n >= N) return;

    float hv[16];
    #pragma unroll
    for (int q = 0; q < 4; ++q) {
        float4 v = *(const float4*)(h + (size_t)n * 16 + q * 4);
        hv[q * 4 + 0] = v.x; hv[q * 4 + 1] = v.y; hv[q * 4 + 2] = v.z; hv[q * 4 + 3] = v.w;
    }

    float t[16];
    #pragma unroll
    for (int j = 0; j < 16; ++j) t[j] = l1b[j];
    #pragma unroll
    for (int k = 0; k < 16; ++k) {
        float hk = hv[k];
        #pragma unroll
        for (int j = 0; j < 16; ++j) t[j] = fmaf(hk, l1w[k * 16 + j], t[j]);
    }

    float acc = l2b[0];
    #pragma unroll
    for (int j = 0; j < 16; ++j) acc = fmaf(fmaxf(t[j], 0.0f), l2w[j], acc);

    out[n] = acc;
}

extern "C" void kernel_launch(void* const* d_in, const int* in_sizes, int n_in,
                              void* d_out, int out_size, void* d_ws, size_t ws_size,
                              hipStream_t stream)
{
    const float* x     = (const float*)d_in[0];
    const int*   ei    = (const int*)  d_in[1];
    const float* ea    = (const float*)d_in[2];
    const float* c1_w1 = (const float*)d_in[3];
    const float* c1_b1 = (const float*)d_in[4];
    const float* c1_w2 = (const float*)d_in[5];
    const float* c1_b2 = (const float*)d_in[6];
    const float* c2_w1 = (const float*)d_in[7];
    const float* c2_b1 = (const float*)d_in[8];
    const float* c2_w2 = (const float*)d_in[9];
    const float* c2_b2 = (const float*)d_in[10];
    const float* l1_w  = (const float*)d_in[11];
    const float* l1_b  = (const float*)d_in[12];
    const float* l2_w  = (const float*)d_in[13];
    const float* l2_b  = (const float*)d_in[14];
    float* out = (float*)d_out;

    const int N = in_sizes[0] / 4;   // 100000
    const int E = in_sizes[2] / 8;   // 1600000

    float* agg1 = (float*)d_ws;
    float* agg2 = agg1 + (size_t)N * 16;

    // zero both aggregation buffers (segment-max identity under >=0 messages)
    hipMemsetAsync(d_ws, 0, (size_t)N * 16 * sizeof(float) * 2, stream);

    const int BLK = 256;
    int egrid = (E + BLK - 1) / BLK;
    int ngrid = (N + BLK - 1) / BLK;

    conv1_edges<<<egrid, BLK, 0, stream>>>(x, ei, ea, c1_w1, c1_b1, c1_w2, c1_b2,
                                           (unsigned int*)agg1, E);
    conv2_edges<<<egrid, BLK, 0, stream>>>(agg1, ei, ea, c2_w1, c2_b1, c2_w2, c2_b2,
                                           (unsigned int*)agg2, E);
    node_head<<<ngrid, BLK, 0, stream>>>(agg2, l1_w, l1_b, l2_w, l2_b, out, N);
}

// Round 2
// 659.499 us; speedup vs baseline: 3.2565x; 3.2565x over previous
//
#include <hip/hip_runtime.h>

#define CHUNK 1024

// ===========================================================================
// CSR-build kernels (edges grouped by src == edge_index[0], the aggregation
// target). pos[] lifecycle: 0 -> degree (hist) -> inclusive scan (scan_*)
// -> start offsets (scatter decrements). csr[] holds edge ids.
// ===========================================================================
__global__ __launch_bounds__(256) void hist_kernel(
    const int* __restrict__ ei, int* __restrict__ pos, int E)
{
    int e = blockIdx.x * 256 + threadIdx.x;
    if (e < E) atomicAdd(&pos[ei[e]], 1);
}

__global__ __launch_bounds__(256) void scan_chunk_sums(
    const int* __restrict__ pos, int* __restrict__ csum, int N)
{
    __shared__ int s[256];
    int base = blockIdx.x * CHUNK;
    int t = threadIdx.x;
    int v = 0;
    #pragma unroll
    for (int i = 0; i < CHUNK / 256; ++i) {
        int idx = base + t + i * 256;
        if (idx < N) v += pos[idx];
    }
    s[t] = v; __syncthreads();
    for (int o = 128; o > 0; o >>= 1) {
        if (t < o) s[t] += s[t + o];
        __syncthreads();
    }
    if (t == 0) csum[blockIdx.x] = s[0];
}

__global__ void scan_chunk_off(
    const int* __restrict__ csum, int* __restrict__ coff, int nch)
{
    if (threadIdx.x == 0 && blockIdx.x == 0) {
        int acc = 0;
        for (int i = 0; i < nch; ++i) { coff[i] = acc; acc += csum[i]; }
    }
}

// in-place INCLUSIVE scan within each 1024-chunk, plus chunk offset
__global__ __launch_bounds__(256) void scan_within(
    int* __restrict__ pos, const int* __restrict__ coff, int N)
{
    __shared__ int s[256];
    int t = threadIdx.x;
    int base = blockIdx.x * CHUNK + t * 4;
    int v0 = 0, v1 = 0, v2 = 0, v3 = 0;
    if (base + 0 < N) v0 = pos[base + 0];
    if (base + 1 < N) v1 = pos[base + 1];
    if (base + 2 < N) v2 = pos[base + 2];
    if (base + 3 < N) v3 = pos[base + 3];
    s[t] = v0 + v1 + v2 + v3;
    __syncthreads();
    for (int o = 1; o < 256; o <<= 1) {
        int add = (t >= o) ? s[t - o] : 0;
        __syncthreads();
        s[t] += add;
        __syncthreads();
    }
    int run = coff[blockIdx.x] + (t > 0 ? s[t - 1] : 0);
    run += v0; if (base + 0 < N) pos[base + 0] = run;
    run += v1; if (base + 1 < N) pos[base + 1] = run;
    run += v2; if (base + 2 < N) pos[base + 2] = run;
    run += v3; if (base + 3 < N) pos[base + 3] = run;
}

__global__ __launch_bounds__(256) void scatter_kernel(
    const int* __restrict__ ei, int* __restrict__ pos,
    int* __restrict__ csr, int E)
{
    int e = blockIdx.x * 256 + threadIdx.x;
    if (e < E) {
        int p = atomicSub(&pos[ei[e]], 1) - 1;
        csr[p] = e;
    }
}

// ===========================================================================
// Node-parallel conv kernels: thread per node, register max, zero atomics.
// ===========================================================================
__global__ __launch_bounds__(256) void conv1_nodes(
    const float* __restrict__ x,    // [N,4]
    const int*   __restrict__ ei,   // [2,E]
    const float* __restrict__ ea,   // [E,8]
    const float* __restrict__ w1, const float* __restrict__ b1,
    const float* __restrict__ w2, const float* __restrict__ b2,
    const int*   __restrict__ pos,  // start offsets
    const int*   __restrict__ csr,  // edge ids grouped by src
    float* __restrict__ agg,        // [N,16]
    int N, int E)
{
    int n = blockIdx.x * 256 + threadIdx.x;
    if (n >= N) return;
    int start = pos[n];
    int end = (n + 1 < N) ? pos[n + 1] : E;

    float4 xs = *(const float4*)(x + (size_t)n * 4);
    float acc[16];
    #pragma unroll
    for (int j = 0; j < 16; ++j) acc[j] = 0.0f;

    for (int k = start; k < end; ++k) {
        int e = csr[k];
        int dst = ei[E + e];
        float m[16];
        m[0] = xs.x; m[1] = xs.y; m[2] = xs.z; m[3] = xs.w;
        float4 xd = *(const float4*)(x + (size_t)dst * 4);
        m[4] = xd.x; m[5] = xd.y; m[6] = xd.z; m[7] = xd.w;
        float4 a0 = *(const float4*)(ea + (size_t)e * 8);
        float4 a1 = *(const float4*)(ea + (size_t)e * 8 + 4);
        m[8]  = a0.x; m[9]  = a0.y; m[10] = a0.z; m[11] = a0.w;
        m[12] = a1.x; m[13] = a1.y; m[14] = a1.z; m[15] = a1.w;

        float h[16];
        #pragma unroll
        for (int j = 0; j < 16; ++j) h[j] = b1[j];
        #pragma unroll
        for (int kk = 0; kk < 16; ++kk) {
            float mk = m[kk];
            #pragma unroll
            for (int j = 0; j < 16; ++j) h[j] = fmaf(mk, w1[kk * 16 + j], h[j]);
        }
        #pragma unroll
        for (int j = 0; j < 16; ++j) h[j] = fmaxf(h[j], 0.0f);

        float o[16];
        #pragma unroll
        for (int j = 0; j < 16; ++j) o[j] = b2[j];
        #pragma unroll
        for (int kk = 0; kk < 16; ++kk) {
            float hk = h[kk];
            #pragma unroll
            for (int j = 0; j < 16; ++j) o[j] = fmaf(hk, w2[kk * 16 + j], o[j]);
        }
        // acc starts at 0, so fmax clamps negatives exactly like relu+segmax+clamp
        #pragma unroll
        for (int j = 0; j < 16; ++j) acc[j] = fmaxf(acc[j], o[j]);
    }

    float4* op = (float4*)(agg + (size_t)n * 16);
    op[0] = make_float4(acc[0],  acc[1],  acc[2],  acc[3]);
    op[1] = make_float4(acc[4],  acc[5],  acc[6],  acc[7]);
    op[2] = make_float4(acc[8],  acc[9],  acc[10], acc[11]);
    op[3] = make_float4(acc[12], acc[13], acc[14], acc[15]);
}

__global__ __launch_bounds__(256) void conv2_nodes_head(
    const float* __restrict__ h,    // [N,16] = agg1
    const int*   __restrict__ ei,   // [2,E]
    const float* __restrict__ ea,   // [E,8]
    const float* __restrict__ w1, const float* __restrict__ b1,   // 40x16
    const float* __restrict__ w2, const float* __restrict__ b2,   // 16x16
    const float* __restrict__ l1w, const float* __restrict__ l1b, // 16x16
    const float* __restrict__ l2w, const float* __restrict__ l2b, // 16x1
    const int*   __restrict__ pos,
    const int*   __restrict__ csr,
    float* __restrict__ out,        // [N,1]
    int N, int E)
{
    int n = blockIdx.x * 256 + threadIdx.x;
    if (n >= N) return;
    int start = pos[n];
    int end = (n + 1 < N) ? pos[n + 1] : E;

    float hs[16];
    #pragma unroll
    for (int q = 0; q < 4; ++q) {
        float4 v = *(const float4*)(h + (size_t)n * 16 + q * 4);
        hs[q*4+0] = v.x; hs[q*4+1] = v.y; hs[q*4+2] = v.z; hs[q*4+3] = v.w;
    }

    float acc[16];
    #pragma unroll
    for (int j = 0; j < 16; ++j) acc[j] = 0.0f;

    for (int k = start; k < end; ++k) {
        int e = csr[k];
        int dst = ei[E + e];
        float m[40];
        #pragma unroll
        for (int j = 0; j < 16; ++j) m[j] = hs[j];
        #pragma unroll
        for (int q = 0; q < 4; ++q) {
            float4 v = *(const float4*)(h + (size_t)dst * 16 + q * 4);
            m[16 + q*4+0] = v.x; m[16 + q*4+1] = v.y;
            m[16 + q*4+2] = v.z; m[16 + q*4+3] = v.w;
        }
        float4 a0 = *(const float4*)(ea + (size_t)e * 8);
        float4 a1 = *(const float4*)(ea + (size_t)e * 8 + 4);
        m[32] = a0.x; m[33] = a0.y; m[34] = a0.z; m[35] = a0.w;
        m[36] = a1.x; m[37] = a1.y; m[38] = a1.z; m[39] = a1.w;

        float t[16];
        #pragma unroll
        for (int j = 0; j < 16; ++j) t[j] = b1[j];
        #pragma unroll
        for (int kk = 0; kk < 40; ++kk) {
            float mk = m[kk];
            #pragma unroll
            for (int j = 0; j < 16; ++j) t[j] = fmaf(mk, w1[kk * 16 + j], t[j]);
        }
        #pragma unroll
        for (int j = 0; j < 16; ++j) t[j] = fmaxf(t[j], 0.0f);

        float o[16];
        #pragma unroll
        for (int j = 0; j < 16; ++j) o[j] = b2[j];
        #pragma unroll
        for (int kk = 0; kk < 16; ++kk) {
            float tk = t[kk];
            #pragma unroll
            for (int j = 0; j < 16; ++j) o[j] = fmaf(tk, w2[kk * 16 + j], o[j]);
        }
        #pragma unroll
        for (int j = 0; j < 16; ++j) acc[j] = fmaxf(acc[j], o[j]);
    }

    // fused head: relu(acc @ l1w + l1b) @ l2w + l2b
    float t2[16];
    #pragma unroll
    for (int j = 0; j < 16; ++j) t2[j] = l1b[j];
    #pragma unroll
    for (int kk = 0; kk < 16; ++kk) {
        float ak = acc[kk];
        #pragma unroll
        for (int j = 0; j < 16; ++j) t2[j] = fmaf(ak, l1w[kk * 16 + j], t2[j]);
    }
    float r = l2b[0];
    #pragma unroll
    for (int j = 0; j < 16; ++j) r = fmaf(fmaxf(t2[j], 0.0f), l2w[j], r);
    out[n] = r;
}

// ===========================================================================
// Fallback path (ws too small for CSR): round-1 atomic kernels with a
// monotonicity-safe test-then-set guard (stale cached reads only cause
// extra atomics, never wrong results, since agg values only increase).
// ===========================================================================
__global__ __launch_bounds__(256) void conv1_edges(
    const float* __restrict__ x, const int* __restrict__ ei,
    const float* __restrict__ ea,
    const float* __restrict__ w1, const float* __restrict__ b1,
    const float* __restrict__ w2, const float* __restrict__ b2,
    unsigned int* __restrict__ agg, int E)
{
    int e = blockIdx.x * blockDim.x + threadIdx.x;
    if (e >= E) return;
    int src = ei[e];
    int dst = ei[E + e];
    float m[16];
    {
        float4 xs = *(const float4*)(x + (size_t)src * 4);
        float4 xd = *(const float4*)(x + (size_t)dst * 4);
        m[0]=xs.x; m[1]=xs.y; m[2]=xs.z; m[3]=xs.w;
        m[4]=xd.x; m[5]=xd.y; m[6]=xd.z; m[7]=xd.w;
        float4 a0 = *(const float4*)(ea + (size_t)e * 8);
        float4 a1 = *(const float4*)(ea + (size_t)e * 8 + 4);
        m[8]=a0.x; m[9]=a0.y; m[10]=a0.z; m[11]=a0.w;
        m[12]=a1.x; m[13]=a1.y; m[14]=a1.z; m[15]=a1.w;
    }
    float h[16];
    #pragma unroll
    for (int j = 0; j < 16; ++j) h[j] = b1[j];
    #pragma unroll
    for (int k = 0; k < 16; ++k) {
        float mk = m[k];
        #pragma unroll
        for (int j = 0; j < 16; ++j) h[j] = fmaf(mk, w1[k*16+j], h[j]);
    }
    #pragma unroll
    for (int j = 0; j < 16; ++j) h[j] = fmaxf(h[j], 0.0f);
    float o[16];
    #pragma unroll
    for (int j = 0; j < 16; ++j) o[j] = b2[j];
    #pragma unroll
    for (int k = 0; k < 16; ++k) {
        float hk = h[k];
        #pragma unroll
        for (int j = 0; j < 16; ++j) o[j] = fmaf(hk, w2[k*16+j], o[j]);
    }
    unsigned int* dstp = agg + (size_t)src * 16;
    #pragma unroll
    for (int j = 0; j < 16; ++j) {
        float v = fmaxf(o[j], 0.0f);
        if (v > __uint_as_float(dstp[j]))
            atomicMax(dstp + j, __float_as_uint(v));
    }
}

__global__ __launch_bounds__(256) void conv2_edges(
    const float* __restrict__ h, const int* __restrict__ ei,
    const float* __restrict__ ea,
    const float* __restrict__ w1, const float* __restrict__ b1,
    const float* __restrict__ w2, const float* __restrict__ b2,
    unsigned int* __restrict__ agg, int E)
{
    int e = blockIdx.x * blockDim.x + threadIdx.x;
    if (e >= E) return;
    int src = ei[e];
    int dst = ei[E + e];
    float m[40];
    #pragma unroll
    for (int q = 0; q < 4; ++q) {
        float4 v = *(const float4*)(h + (size_t)src * 16 + q * 4);
        m[q*4+0]=v.x; m[q*4+1]=v.y; m[q*4+2]=v.z; m[q*4+3]=v.w;
    }
    #pragma unroll
    for (int q = 0; q < 4; ++q) {
        float4 v = *(const float4*)(h + (size_t)dst * 16 + q * 4);
        m[16+q*4+0]=v.x; m[16+q*4+1]=v.y; m[16+q*4+2]=v.z; m[16+q*4+3]=v.w;
    }
    {
        float4 a0 = *(const float4*)(ea + (size_t)e * 8);
        float4 a1 = *(const float4*)(ea + (size_t)e * 8 + 4);
        m[32]=a0.x; m[33]=a0.y; m[34]=a0.z; m[35]=a0.w;
        m[36]=a1.x; m[37]=a1.y; m[38]=a1.z; m[39]=a1.w;
    }
    float t[16];
    #pragma unroll
    for (int j = 0; j < 16; ++j) t[j] = b1[j];
    #pragma unroll
    for (int k = 0; k < 40; ++k) {
        float mk = m[k];
        #pragma unroll
        for (int j = 0; j < 16; ++j) t[j] = fmaf(mk, w1[k*16+j], t[j]);
    }
    #pragma unroll
    for (int j = 0; j < 16; ++j) t[j] = fmaxf(t[j], 0.0f);
    float o[16];
    #pragma unroll
    for (int j = 0; j < 16; ++j) o[j] = b2[j];
    #pragma unroll
    for (int k = 0; k < 16; ++k) {
        float tk = t[k];
        #pragma unroll
        for (int j = 0; j < 16; ++j) o[j] = fmaf(tk, w2[k*16+j], o[j]);
    }
    unsigned int* dstp = agg + (size_t)src * 16;
    #pragma unroll
    for (int j = 0; j < 16; ++j) {
        float v = fmaxf(o[j], 0.0f);
        if (v > __uint_as_float(dstp[j]))
            atomicMax(dstp + j, __float_as_uint(v));
    }
}

__global__ __launch_bounds__(256) void node_head(
    const float* __restrict__ h,
    const float* __restrict__ l1w, const float* __restrict__ l1b,
    const float* __restrict__ l2w, const float* __restrict__ l2b,
    float* __restrict__ out, int N)
{
    int n = blockIdx.x * blockDim.x + threadIdx.x;
    if (n >= N) return;
    float hv[16];
    #pragma unroll
    for (int q = 0; q < 4; ++q) {
        float4 v = *(const float4*)(h + (size_t)n * 16 + q * 4);
        hv[q*4+0]=v.x; hv[q*4+1]=v.y; hv[q*4+2]=v.z; hv[q*4+3]=v.w;
    }
    float t[16];
    #pragma unroll
    for (int j = 0; j < 16; ++j) t[j] = l1b[j];
    #pragma unroll
    for (int k = 0; k < 16; ++k) {
        float hk = hv[k];
        #pragma unroll
        for (int j = 0; j < 16; ++j) t[j] = fmaf(hk, l1w[k*16+j], t[j]);
    }
    float acc = l2b[0];
    #pragma unroll
    for (int j = 0; j < 16; ++j) acc = fmaf(fmaxf(t[j], 0.0f), l2w[j], acc);
    out[n] = acc;
}

// ===========================================================================
extern "C" void kernel_launch(void* const* d_in, const int* in_sizes, int n_in,
                              void* d_out, int out_size, void* d_ws, size_t ws_size,
                              hipStream_t stream)
{
    const float* x     = (const float*)d_in[0];
    const int*   ei    = (const int*)  d_in[1];
    const float* ea    = (const float*)d_in[2];
    const float* c1_w1 = (const float*)d_in[3];
    const float* c1_b1 = (const float*)d_in[4];
    const float* c1_w2 = (const float*)d_in[5];
    const float* c1_b2 = (const float*)d_in[6];
    const float* c2_w1 = (const float*)d_in[7];
    const float* c2_b1 = (const float*)d_in[8];
    const float* c2_w2 = (const float*)d_in[9];
    const float* c2_b2 = (const float*)d_in[10];
    const float* l1_w  = (const float*)d_in[11];
    const float* l1_b  = (const float*)d_in[12];
    const float* l2_w  = (const float*)d_in[13];
    const float* l2_b  = (const float*)d_in[14];
    float* out = (float*)d_out;

    const int N = in_sizes[0] / 4;   // 100000
    const int E = in_sizes[2] / 8;   // 1600000
    const int nch = (N + CHUNK - 1) / CHUNK;

    const int BLK = 256;
    const int egrid = (E + BLK - 1) / BLK;
    const int ngrid = (N + BLK - 1) / BLK;

    // CSR-path workspace layout (all offsets 16B-aligned)
    size_t agg1_off = 0;                                   // N*16 floats
    size_t pos_off  = agg1_off + (size_t)N * 16 * 4;       // N ints
    size_t csr_off  = pos_off  + (size_t)((N * 4 + 15) & ~15);  // E ints
    size_t csum_off = csr_off  + (size_t)E * 4;            // nch ints
    size_t coff_off = csum_off + (size_t)((nch * 4 + 15) & ~15);
    size_t need     = coff_off + (size_t)nch * 4 + 64;

    if (ws_size >= need) {
        float* agg1 = (float*)((char*)d_ws + agg1_off);
        int*   pos  = (int*)  ((char*)d_ws + pos_off);
        int*   csr  = (int*)  ((char*)d_ws + csr_off);
        int*   csum = (int*)  ((char*)d_ws + csum_off);
        int*   coff = (int*)  ((char*)d_ws + coff_off);

        hipMemsetAsync(pos, 0, (size_t)N * 4, stream);
        hist_kernel<<<egrid, BLK, 0, stream>>>(ei, pos, E);
        scan_chunk_sums<<<nch, BLK, 0, stream>>>(pos, csum, N);
        scan_chunk_off<<<1, 64, 0, stream>>>(csum, coff, nch);
        scan_within<<<nch, BLK, 0, stream>>>(pos, coff, N);
        scatter_kernel<<<egrid, BLK, 0, stream>>>(ei, pos, csr, E);
        conv1_nodes<<<ngrid, BLK, 0, stream>>>(x, ei, ea, c1_w1, c1_b1, c1_w2, c1_b2,
                                               pos, csr, agg1, N, E);
        conv2_nodes_head<<<ngrid, BLK, 0, stream>>>(agg1, ei, ea, c2_w1, c2_b1, c2_w2, c2_b2,
                                                    l1_w, l1_b, l2_w, l2_b,
                                                    pos, csr, out, N, E);
    } else {
        // fallback: atomic path (needs 12.8 MB)
        float* agg1 = (float*)d_ws;
        float* agg2 = agg1 + (size_t)N * 16;
        hipMemsetAsync(d_ws, 0, (size_t)N * 16 * 4 * 2, stream);
        conv1_edges<<<egrid, BLK, 0, stream>>>(x, ei, ea, c1_w1, c1_b1, c1_w2, c1_b2,
                                               (unsigned int*)agg1, E);
        conv2_edges<<<egrid, BLK, 0, stream>>>(agg1, ei, ea, c2_w1, c2_b1, c2_w2, c2_b2,
                                               (unsigned int*)agg2, E);
        node_head<<<ngrid, BLK, 0, stream>>>(agg2, l1_w, l1_b, l2_w, l2_b, out, N);
    }
}

// Round 3
// 456.639 us; speedup vs baseline: 4.7031x; 1.4442x over previous
//
#include <hip/hip_runtime.h>

#define CHUNK 1024

// ===========================================================================
// ============================ TIER A kernels ===============================
// CSR build with payload permutation: edges grouped by src; dst and ea are
// physically reordered so conv kernels stream them coalesced.
// ===========================================================================

// pass 1: r[e] = rank of edge e within its src bucket; deg[src] histogram
__global__ __launch_bounds__(256) void rank_kernel(
    const int* __restrict__ ei, int* __restrict__ deg,
    int* __restrict__ r, int E)
{
    int e = blockIdx.x * 256 + threadIdx.x;
    if (e < E) r[e] = atomicAdd(&deg[ei[e]], 1);
}

__global__ __launch_bounds__(256) void scan_chunk_sums(
    const int* __restrict__ v, int* __restrict__ csum, int N)
{
    __shared__ int s[256];
    int base = blockIdx.x * CHUNK;
    int t = threadIdx.x;
    int acc = 0;
    #pragma unroll
    for (int i = 0; i < CHUNK / 256; ++i) {
        int idx = base + t + i * 256;
        if (idx < N) acc += v[idx];
    }
    s[t] = acc; __syncthreads();
    for (int o = 128; o > 0; o >>= 1) {
        if (t < o) s[t] += s[t + o];
        __syncthreads();
    }
    if (t == 0) csum[blockIdx.x] = s[0];
}

__global__ void scan_chunk_off(
    const int* __restrict__ csum, int* __restrict__ coff, int nch)
{
    if (threadIdx.x == 0 && blockIdx.x == 0) {
        int acc = 0;
        for (int i = 0; i < nch; ++i) { coff[i] = acc; acc += csum[i]; }
    }
}

// EXCLUSIVE scan of deg -> pos (start offsets), chunked
__global__ __launch_bounds__(256) void scan_within_excl(
    const int* __restrict__ deg, int* __restrict__ pos,
    const int* __restrict__ coff, int N)
{
    __shared__ int s[256];
    int t = threadIdx.x;
    int base = blockIdx.x * CHUNK + t * 4;
    int v0 = 0, v1 = 0, v2 = 0, v3 = 0;
    if (base + 0 < N) v0 = deg[base + 0];
    if (base + 1 < N) v1 = deg[base + 1];
    if (base + 2 < N) v2 = deg[base + 2];
    if (base + 3 < N) v3 = deg[base + 3];
    s[t] = v0 + v1 + v2 + v3;
    __syncthreads();
    for (int o = 1; o < 256; o <<= 1) {
        int add = (t >= o) ? s[t - o] : 0;
        __syncthreads();
        s[t] += add;
        __syncthreads();
    }
    int run = coff[blockIdx.x] + (t > 0 ? s[t - 1] : 0);
    if (base + 0 < N) pos[base + 0] = run; run += v0;
    if (base + 1 < N) pos[base + 1] = run; run += v1;
    if (base + 2 < N) pos[base + 2] = run; run += v2;
    if (base + 3 < N) pos[base + 3] = run;
}

// pass 2: atomic-free payload scatter into CSR order
__global__ __launch_bounds__(256) void scatter_perm(
    const int* __restrict__ ei, const float* __restrict__ ea,
    const int* __restrict__ pos, const int* __restrict__ r,
    int* __restrict__ dst_perm, float* __restrict__ ea_perm, int E)
{
    int e = blockIdx.x * 256 + threadIdx.x;
    if (e >= E) return;
    int s = ei[e];
    int d = ei[E + e];
    int p = pos[s] + r[e];
    dst_perm[p] = d;
    float4 a0 = *(const float4*)(ea + (size_t)e * 8);
    float4 a1 = *(const float4*)(ea + (size_t)e * 8 + 4);
    *(float4*)(ea_perm + (size_t)p * 8)     = a0;
    *(float4*)(ea_perm + (size_t)p * 8 + 4) = a1;
}

// ---------------------------------------------------------------------------
// conv1: 8 lanes per node, streaming ea_perm/dst_perm, shfl-xor max reduce
// ---------------------------------------------------------------------------
__global__ __launch_bounds__(256) void conv1_g8(
    const float* __restrict__ x,        // [N,4]
    const int*   __restrict__ dst_perm, // [E]
    const float* __restrict__ ea_perm,  // [E,8]
    const float* __restrict__ w1, const float* __restrict__ b1,
    const float* __restrict__ w2, const float* __restrict__ b2,
    const int*   __restrict__ pos,
    float* __restrict__ agg,            // [N,16]
    int N, int E)
{
    int tid = threadIdx.x;
    int n = blockIdx.x * 32 + (tid >> 3);
    if (n >= N) return;
    int g = tid & 7;
    int start = pos[n];
    int end = (n + 1 < N) ? pos[n + 1] : E;

    // loop-invariant src part: b1 + x[n] @ w1[0:4,:]
    float4 xs = *(const float4*)(x + (size_t)n * 4);
    float ts[16];
    #pragma unroll
    for (int j = 0; j < 16; ++j) ts[j] = b1[j];
    #pragma unroll
    for (int j = 0; j < 16; ++j) {
        ts[j] = fmaf(xs.x, w1[0 * 16 + j], ts[j]);
        ts[j] = fmaf(xs.y, w1[1 * 16 + j], ts[j]);
        ts[j] = fmaf(xs.z, w1[2 * 16 + j], ts[j]);
        ts[j] = fmaf(xs.w, w1[3 * 16 + j], ts[j]);
    }

    float acc[16];
    #pragma unroll
    for (int j = 0; j < 16; ++j) acc[j] = 0.0f;

    for (int k = start + g; k < end; k += 8) {
        int dst = dst_perm[k];
        float4 xd = *(const float4*)(x + (size_t)dst * 4);
        float4 a0 = *(const float4*)(ea_perm + (size_t)k * 8);
        float4 a1 = *(const float4*)(ea_perm + (size_t)k * 8 + 4);
        float ae[8] = {a0.x, a0.y, a0.z, a0.w, a1.x, a1.y, a1.z, a1.w};

        float t[16];
        #pragma unroll
        for (int j = 0; j < 16; ++j) {
            float v = ts[j];
            v = fmaf(xd.x, w1[4 * 16 + j], v);
            v = fmaf(xd.y, w1[5 * 16 + j], v);
            v = fmaf(xd.z, w1[6 * 16 + j], v);
            v = fmaf(xd.w, w1[7 * 16 + j], v);
            #pragma unroll
            for (int kk = 0; kk < 8; ++kk)
                v = fmaf(ae[kk], w1[(8 + kk) * 16 + j], v);
            t[j] = fmaxf(v, 0.0f);
        }

        float o[16];
        #pragma unroll
        for (int j = 0; j < 16; ++j) o[j] = b2[j];
        #pragma unroll
        for (int kk = 0; kk < 16; ++kk) {
            float tk = t[kk];
            #pragma unroll
            for (int j = 0; j < 16; ++j) o[j] = fmaf(tk, w2[kk * 16 + j], o[j]);
        }
        #pragma unroll
        for (int j = 0; j < 16; ++j) acc[j] = fmaxf(acc[j], o[j]);
    }

    // butterfly max across the 8 lanes of the group
    #pragma unroll
    for (int mask = 1; mask < 8; mask <<= 1) {
        #pragma unroll
        for (int j = 0; j < 16; ++j)
            acc[j] = fmaxf(acc[j], __shfl_xor(acc[j], mask, 64));
    }

    // coalesced store: lane g writes channels [2g, 2g+1]
    float2 st = make_float2(acc[2 * g], acc[2 * g + 1]);
    *(float2*)(agg + (size_t)n * 16 + 2 * g) = st;
}

// transform agg1 -> hw_s (in place, +b1) and hw_d for conv2
__global__ __launch_bounds__(256) void hw_transform(
    float* __restrict__ agg1,      // [N,16], overwritten with hw_s
    float* __restrict__ hw_d,      // [N,16]
    const float* __restrict__ w1,  // [40,16]
    const float* __restrict__ b1,  // [16]
    int N)
{
    int n = blockIdx.x * 256 + threadIdx.x;
    if (n >= N) return;
    float h[16];
    #pragma unroll
    for (int q = 0; q < 4; ++q) {
        float4 v = *(const float4*)(agg1 + (size_t)n * 16 + q * 4);
        h[q*4+0] = v.x; h[q*4+1] = v.y; h[q*4+2] = v.z; h[q*4+3] = v.w;
    }
    float hs[16], hd[16];
    #pragma unroll
    for (int j = 0; j < 16; ++j) { hs[j] = b1[j]; hd[j] = 0.0f; }
    #pragma unroll
    for (int k = 0; k < 16; ++k) {
        float hk = h[k];
        #pragma unroll
        for (int j = 0; j < 16; ++j) {
            hs[j] = fmaf(hk, w1[k * 16 + j], hs[j]);
            hd[j] = fmaf(hk, w1[(16 + k) * 16 + j], hd[j]);
        }
    }
    float4* ps = (float4*)(agg1 + (size_t)n * 16);
    float4* pd = (float4*)(hw_d + (size_t)n * 16);
    ps[0] = make_float4(hs[0], hs[1], hs[2], hs[3]);
    ps[1] = make_float4(hs[4], hs[5], hs[6], hs[7]);
    ps[2] = make_float4(hs[8], hs[9], hs[10], hs[11]);
    ps[3] = make_float4(hs[12], hs[13], hs[14], hs[15]);
    pd[0] = make_float4(hd[0], hd[1], hd[2], hd[3]);
    pd[1] = make_float4(hd[4], hd[5], hd[6], hd[7]);
    pd[2] = make_float4(hd[8], hd[9], hd[10], hd[11]);
    pd[3] = make_float4(hd[12], hd[13], hd[14], hd[15]);
}

// ---------------------------------------------------------------------------
// conv2 + head fused: 8 lanes per node, using precomputed hw_s / hw_d
// ---------------------------------------------------------------------------
__global__ __launch_bounds__(256) void conv2_g8_head(
    const float* __restrict__ hw_s,     // [N,16] = agg1 transformed (+b1)
    const float* __restrict__ hw_d,     // [N,16]
    const int*   __restrict__ dst_perm, // [E]
    const float* __restrict__ ea_perm,  // [E,8]
    const float* __restrict__ w1,       // [40,16] (rows 32:40 used)
    const float* __restrict__ w2, const float* __restrict__ b2,
    const float* __restrict__ l1w, const float* __restrict__ l1b,
    const float* __restrict__ l2w, const float* __restrict__ l2b,
    const int*   __restrict__ pos,
    float* __restrict__ out,            // [N,1]
    int N, int E)
{
    int tid = threadIdx.x;
    int n = blockIdx.x * 32 + (tid >> 3);
    if (n >= N) return;
    int g = tid & 7;
    int start = pos[n];
    int end = (n + 1 < N) ? pos[n + 1] : E;

    float ts[16];
    #pragma unroll
    for (int q = 0; q < 4; ++q) {
        float4 v = *(const float4*)(hw_s + (size_t)n * 16 + q * 4);
        ts[q*4+0] = v.x; ts[q*4+1] = v.y; ts[q*4+2] = v.z; ts[q*4+3] = v.w;
    }

    float acc[16];
    #pragma unroll
    for (int j = 0; j < 16; ++j) acc[j] = 0.0f;

    for (int k = start + g; k < end; k += 8) {
        int dst = dst_perm[k];
        float4 a0 = *(const float4*)(ea_perm + (size_t)k * 8);
        float4 a1 = *(const float4*)(ea_perm + (size_t)k * 8 + 4);
        float ae[8] = {a0.x, a0.y, a0.z, a0.w, a1.x, a1.y, a1.z, a1.w};

        float hd[16];
        #pragma unroll
        for (int q = 0; q < 4; ++q) {
            float4 v = *(const float4*)(hw_d + (size_t)dst * 16 + q * 4);
            hd[q*4+0] = v.x; hd[q*4+1] = v.y; hd[q*4+2] = v.z; hd[q*4+3] = v.w;
        }

        float t[16];
        #pragma unroll
        for (int j = 0; j < 16; ++j) {
            float v = ts[j] + hd[j];
            #pragma unroll
            for (int kk = 0; kk < 8; ++kk)
                v = fmaf(ae[kk], w1[(32 + kk) * 16 + j], v);
            t[j] = fmaxf(v, 0.0f);
        }

        float o[16];
        #pragma unroll
        for (int j = 0; j < 16; ++j) o[j] = b2[j];
        #pragma unroll
        for (int kk = 0; kk < 16; ++kk) {
            float tk = t[kk];
            #pragma unroll
            for (int j = 0; j < 16; ++j) o[j] = fmaf(tk, w2[kk * 16 + j], o[j]);
        }
        #pragma unroll
        for (int j = 0; j < 16; ++j) acc[j] = fmaxf(acc[j], o[j]);
    }

    #pragma unroll
    for (int mask = 1; mask < 8; mask <<= 1) {
        #pragma unroll
        for (int j = 0; j < 16; ++j)
            acc[j] = fmaxf(acc[j], __shfl_xor(acc[j], mask, 64));
    }

    // head (all lanes compute, lane 0 stores): relu(acc@l1+b) @ l2 + b
    float t2[16];
    #pragma unroll
    for (int j = 0; j < 16; ++j) t2[j] = l1b[j];
    #pragma unroll
    for (int kk = 0; kk < 16; ++kk) {
        float ak = acc[kk];
        #pragma unroll
        for (int j = 0; j < 16; ++j) t2[j] = fmaf(ak, l1w[kk * 16 + j], t2[j]);
    }
    float r = l2b[0];
    #pragma unroll
    for (int j = 0; j < 16; ++j) r = fmaf(fmaxf(t2[j], 0.0f), l2w[j], r);
    if (g == 0) out[n] = r;
}

// ===========================================================================
// ============================ TIER B kernels ===============================
// Round-2 CSR path (edge-id indirection), used if ws is too small for tier A.
// ===========================================================================
__global__ __launch_bounds__(256) void hist_kernel(
    const int* __restrict__ ei, int* __restrict__ pos, int E)
{
    int e = blockIdx.x * 256 + threadIdx.x;
    if (e < E) atomicAdd(&pos[ei[e]], 1);
}

__global__ __launch_bounds__(256) void scan_within_incl(
    int* __restrict__ pos, const int* __restrict__ coff, int N)
{
    __shared__ int s[256];
    int t = threadIdx.x;
    int base = blockIdx.x * CHUNK + t * 4;
    int v0 = 0, v1 = 0, v2 = 0, v3 = 0;
    if (base + 0 < N) v0 = pos[base + 0];
    if (base + 1 < N) v1 = pos[base + 1];
    if (base + 2 < N) v2 = pos[base + 2];
    if (base + 3 < N) v3 = pos[base + 3];
    s[t] = v0 + v1 + v2 + v3;
    __syncthreads();
    for (int o = 1; o < 256; o <<= 1) {
        int add = (t >= o) ? s[t - o] : 0;
        __syncthreads();
        s[t] += add;
        __syncthreads();
    }
    int run = coff[blockIdx.x] + (t > 0 ? s[t - 1] : 0);
    run += v0; if (base + 0 < N) pos[base + 0] = run;
    run += v1; if (base + 1 < N) pos[base + 1] = run;
    run += v2; if (base + 2 < N) pos[base + 2] = run;
    run += v3; if (base + 3 < N) pos[base + 3] = run;
}

__global__ __launch_bounds__(256) void scatter_kernel(
    const int* __restrict__ ei, int* __restrict__ pos,
    int* __restrict__ csr, int E)
{
    int e = blockIdx.x * 256 + threadIdx.x;
    if (e < E) {
        int p = atomicSub(&pos[ei[e]], 1) - 1;
        csr[p] = e;
    }
}

__global__ __launch_bounds__(256) void conv1_nodes(
    const float* __restrict__ x, const int* __restrict__ ei,
    const float* __restrict__ ea,
    const float* __restrict__ w1, const float* __restrict__ b1,
    const float* __restrict__ w2, const float* __restrict__ b2,
    const int* __restrict__ pos, const int* __restrict__ csr,
    float* __restrict__ agg, int N, int E)
{
    int n = blockIdx.x * 256 + threadIdx.x;
    if (n >= N) return;
    int start = pos[n];
    int end = (n + 1 < N) ? pos[n + 1] : E;
    float4 xs = *(const float4*)(x + (size_t)n * 4);
    float acc[16];
    #pragma unroll
    for (int j = 0; j < 16; ++j) acc[j] = 0.0f;
    for (int k = start; k < end; ++k) {
        int e = csr[k];
        int dst = ei[E + e];
        float m[16];
        m[0]=xs.x; m[1]=xs.y; m[2]=xs.z; m[3]=xs.w;
        float4 xd = *(const float4*)(x + (size_t)dst * 4);
        m[4]=xd.x; m[5]=xd.y; m[6]=xd.z; m[7]=xd.w;
        float4 a0 = *(const float4*)(ea + (size_t)e * 8);
        float4 a1 = *(const float4*)(ea + (size_t)e * 8 + 4);
        m[8]=a0.x; m[9]=a0.y; m[10]=a0.z; m[11]=a0.w;
        m[12]=a1.x; m[13]=a1.y; m[14]=a1.z; m[15]=a1.w;
        float h[16];
        #pragma unroll
        for (int j = 0; j < 16; ++j) h[j] = b1[j];
        #pragma unroll
        for (int kk = 0; kk < 16; ++kk) {
            float mk = m[kk];
            #pragma unroll
            for (int j = 0; j < 16; ++j) h[j] = fmaf(mk, w1[kk*16+j], h[j]);
        }
        #pragma unroll
        for (int j = 0; j < 16; ++j) h[j] = fmaxf(h[j], 0.0f);
        float o[16];
        #pragma unroll
        for (int j = 0; j < 16; ++j) o[j] = b2[j];
        #pragma unroll
        for (int kk = 0; kk < 16; ++kk) {
            float hk = h[kk];
            #pragma unroll
            for (int j = 0; j < 16; ++j) o[j] = fmaf(hk, w2[kk*16+j], o[j]);
        }
        #pragma unroll
        for (int j = 0; j < 16; ++j) acc[j] = fmaxf(acc[j], o[j]);
    }
    float4* op = (float4*)(agg + (size_t)n * 16);
    op[0] = make_float4(acc[0],acc[1],acc[2],acc[3]);
    op[1] = make_float4(acc[4],acc[5],acc[6],acc[7]);
    op[2] = make_float4(acc[8],acc[9],acc[10],acc[11]);
    op[3] = make_float4(acc[12],acc[13],acc[14],acc[15]);
}

__global__ __launch_bounds__(256) void conv2_nodes_head(
    const float* __restrict__ h, const int* __restrict__ ei,
    const float* __restrict__ ea,
    const float* __restrict__ w1, const float* __restrict__ b1,
    const float* __restrict__ w2, const float* __restrict__ b2,
    const float* __restrict__ l1w, const float* __restrict__ l1b,
    const float* __restrict__ l2w, const float* __restrict__ l2b,
    const int* __restrict__ pos, const int* __restrict__ csr,
    float* __restrict__ out, int N, int E)
{
    int n = blockIdx.x * 256 + threadIdx.x;
    if (n >= N) return;
    int start = pos[n];
    int end = (n + 1 < N) ? pos[n + 1] : E;
    float hs[16];
    #pragma unroll
    for (int q = 0; q < 4; ++q) {
        float4 v = *(const float4*)(h + (size_t)n * 16 + q * 4);
        hs[q*4+0]=v.x; hs[q*4+1]=v.y; hs[q*4+2]=v.z; hs[q*4+3]=v.w;
    }
    float acc[16];
    #pragma unroll
    for (int j = 0; j < 16; ++j) acc[j] = 0.0f;
    for (int k = start; k < end; ++k) {
        int e = csr[k];
        int dst = ei[E + e];
        float m[40];
        #pragma unroll
        for (int j = 0; j < 16; ++j) m[j] = hs[j];
        #pragma unroll
        for (int q = 0; q < 4; ++q) {
            float4 v = *(const float4*)(h + (size_t)dst * 16 + q * 4);
            m[16+q*4+0]=v.x; m[16+q*4+1]=v.y; m[16+q*4+2]=v.z; m[16+q*4+3]=v.w;
        }
        float4 a0 = *(const float4*)(ea + (size_t)e * 8);
        float4 a1 = *(const float4*)(ea + (size_t)e * 8 + 4);
        m[32]=a0.x; m[33]=a0.y; m[34]=a0.z; m[35]=a0.w;
        m[36]=a1.x; m[37]=a1.y; m[38]=a1.z; m[39]=a1.w;
        float t[16];
        #pragma unroll
        for (int j = 0; j < 16; ++j) t[j] = b1[j];
        #pragma unroll
        for (int kk = 0; kk < 40; ++kk) {
            float mk = m[kk];
            #pragma unroll
            for (int j = 0; j < 16; ++j) t[j] = fmaf(mk, w1[kk*16+j], t[j]);
        }
        #pragma unroll
        for (int j = 0; j < 16; ++j) t[j] = fmaxf(t[j], 0.0f);
        float o[16];
        #pragma unroll
        for (int j = 0; j < 16; ++j) o[j] = b2[j];
        #pragma unroll
        for (int kk = 0; kk < 16; ++kk) {
            float tk = t[kk];
            #pragma unroll
            for (int j = 0; j < 16; ++j) o[j] = fmaf(tk, w2[kk*16+j], o[j]);
        }
        #pragma unroll
        for (int j = 0; j < 16; ++j) acc[j] = fmaxf(acc[j], o[j]);
    }
    float t2[16];
    #pragma unroll
    for (int j = 0; j < 16; ++j) t2[j] = l1b[j];
    #pragma unroll
    for (int kk = 0; kk < 16; ++kk) {
        float ak = acc[kk];
        #pragma unroll
        for (int j = 0; j < 16; ++j) t2[j] = fmaf(ak, l1w[kk*16+j], t2[j]);
    }
    float r = l2b[0];
    #pragma unroll
    for (int j = 0; j < 16; ++j) r = fmaf(fmaxf(t2[j], 0.0f), l2w[j], r);
    out[n] = r;
}

// ===========================================================================
extern "C" void kernel_launch(void* const* d_in, const int* in_sizes, int n_in,
                              void* d_out, int out_size, void* d_ws, size_t ws_size,
                              hipStream_t stream)
{
    const float* x     = (const float*)d_in[0];
    const int*   ei    = (const int*)  d_in[1];
    const float* ea    = (const float*)d_in[2];
    const float* c1_w1 = (const float*)d_in[3];
    const float* c1_b1 = (const float*)d_in[4];
    const float* c1_w2 = (const float*)d_in[5];
    const float* c1_b2 = (const float*)d_in[6];
    const float* c2_w1 = (const float*)d_in[7];
    const float* c2_b1 = (const float*)d_in[8];
    const float* c2_w2 = (const float*)d_in[9];
    const float* c2_b2 = (const float*)d_in[10];
    const float* l1_w  = (const float*)d_in[11];
    const float* l1_b  = (const float*)d_in[12];
    const float* l2_w  = (const float*)d_in[13];
    const float* l2_b  = (const float*)d_in[14];
    float* out = (float*)d_out;

    const int N = in_sizes[0] / 4;   // 100000
    const int E = in_sizes[2] / 8;   // 1600000
    const int nch = (N + CHUNK - 1) / CHUNK;

    const int BLK = 256;
    const int egrid = (E + BLK - 1) / BLK;
    const int ngrid = (N + BLK - 1) / BLK;
    const int ggrid = (N + 31) / 32;       // 8 lanes/node, 32 nodes/block

    // ---- Tier A workspace layout (16B-aligned pieces) ----
    size_t szN16 = (size_t)N * 16 * 4;     // 6.4 MB
    size_t szN   = ((size_t)N * 4 + 15) & ~(size_t)15;
    size_t szE   = (size_t)E * 4;          // 6.4 MB
    size_t szEA  = (size_t)E * 32;         // 51.2 MB

    size_t agg1_off = 0;                       // agg1 -> hw_s (in place)
    size_t hwd_off  = agg1_off + szN16;
    size_t deg_off  = hwd_off  + szN16;
    size_t posA_off = deg_off  + szN;
    size_t r_off    = posA_off + szN;
    size_t dstp_off = r_off    + szE;
    size_t eap_off  = dstp_off + szE;
    size_t csA_off  = eap_off  + szEA;
    size_t cfA_off  = csA_off  + 4096;
    size_t needA    = cfA_off  + 4096;

    if (ws_size >= needA) {
        float* agg1 = (float*)((char*)d_ws + agg1_off);
        float* hw_d = (float*)((char*)d_ws + hwd_off);
        int*   deg  = (int*)  ((char*)d_ws + deg_off);
        int*   pos  = (int*)  ((char*)d_ws + posA_off);
        int*   r    = (int*)  ((char*)d_ws + r_off);
        int*   dstp = (int*)  ((char*)d_ws + dstp_off);
        float* eap  = (float*)((char*)d_ws + eap_off);
        int*   csum = (int*)  ((char*)d_ws + csA_off);
        int*   coff = (int*)  ((char*)d_ws + cfA_off);

        hipMemsetAsync(deg, 0, (size_t)N * 4, stream);
        rank_kernel<<<egrid, BLK, 0, stream>>>(ei, deg, r, E);
        scan_chunk_sums<<<nch, BLK, 0, stream>>>(deg, csum, N);
        scan_chunk_off<<<1, 64, 0, stream>>>(csum, coff, nch);
        scan_within_excl<<<nch, BLK, 0, stream>>>(deg, pos, coff, N);
        scatter_perm<<<egrid, BLK, 0, stream>>>(ei, ea, pos, r, dstp, eap, E);
        conv1_g8<<<ggrid, BLK, 0, stream>>>(x, dstp, eap, c1_w1, c1_b1, c1_w2, c1_b2,
                                            pos, agg1, N, E);
        hw_transform<<<ngrid, BLK, 0, stream>>>(agg1, hw_d, c2_w1, c2_b1, N);
        conv2_g8_head<<<ggrid, BLK, 0, stream>>>(agg1, hw_d, dstp, eap,
                                                 c2_w1, c2_w2, c2_b2,
                                                 l1_w, l1_b, l2_w, l2_b,
                                                 pos, out, N, E);
        return;
    }

    // ---- Tier B: round-2 CSR path (~13.2 MB) ----
    size_t agg1B_off = 0;
    size_t posB_off  = agg1B_off + szN16;
    size_t csrB_off  = posB_off  + szN;
    size_t csB_off   = csrB_off  + szE;
    size_t cfB_off   = csB_off   + 4096;
    size_t needB     = cfB_off   + 4096;
    (void)needB;

    float* agg1 = (float*)((char*)d_ws + agg1B_off);
    int*   pos  = (int*)  ((char*)d_ws + posB_off);
    int*   csr  = (int*)  ((char*)d_ws + csrB_off);
    int*   csum = (int*)  ((char*)d_ws + csB_off);
    int*   coff = (int*)  ((char*)d_ws + cfB_off);

    hipMemsetAsync(pos, 0, (size_t)N * 4, stream);
    hist_kernel<<<egrid, BLK, 0, stream>>>(ei, pos, E);
    scan_chunk_sums<<<nch, BLK, 0, stream>>>(pos, csum, N);
    scan_chunk_off<<<1, 64, 0, stream>>>(csum, coff, nch);
    scan_within_incl<<<nch, BLK, 0, stream>>>(pos, coff, N);
    scatter_kernel<<<egrid, BLK, 0, stream>>>(ei, pos, csr, E);
    conv1_nodes<<<ngrid, BLK, 0, stream>>>(x, ei, ea, c1_w1, c1_b1, c1_w2, c1_b2,
                                           pos, csr, agg1, N, E);
    conv2_nodes_head<<<ngrid, BLK, 0, stream>>>(agg1, ei, ea, c2_w1, c2_b1, c2_w2, c2_b2,
                                                l1_w, l1_b, l2_w, l2_b,
                                                pos, csr, out, N, E);
}

// Round 4
// 443.078 us; speedup vs baseline: 4.8471x; 1.0306x over previous
//
#include <hip/hip_runtime.h>
#include <hip/hip_fp16.h>

#define CHUNK 1024

__device__ __forceinline__ unsigned int pack2(float a, float b) {
    __half2 h = __floats2half2_rn(a, b);
    return *(unsigned int*)&h;
}
__device__ __forceinline__ float2 unpack2(unsigned int u) {
    __half2 h = *(__half2*)&u;
    return __half22float2(h);
}

// ===========================================================================
// CSR build: edges grouped by src (the aggregation target); payload (dst,
// ea-as-fp16) physically permuted so conv kernels stream it coalesced.
// ===========================================================================

// pass 1: r[e] = rank of edge e within its src bucket; deg[] histogram
__global__ __launch_bounds__(256) void rank_kernel(
    const int* __restrict__ ei, int* __restrict__ deg,
    unsigned short* __restrict__ r, int E)
{
    int e = blockIdx.x * 256 + threadIdx.x;
    if (e < E) r[e] = (unsigned short)atomicAdd(&deg[ei[e]], 1);
}

__global__ __launch_bounds__(256) void scan_chunk_sums(
    const int* __restrict__ v, int* __restrict__ csum, int N)
{
    __shared__ int s[256];
    int base = blockIdx.x * CHUNK;
    int t = threadIdx.x;
    int acc = 0;
    #pragma unroll
    for (int i = 0; i < CHUNK / 256; ++i) {
        int idx = base + t + i * 256;
        if (idx < N) acc += v[idx];
    }
    s[t] = acc; __syncthreads();
    for (int o = 128; o > 0; o >>= 1) {
        if (t < o) s[t] += s[t + o];
        __syncthreads();
    }
    if (t == 0) csum[blockIdx.x] = s[0];
}

__global__ void scan_chunk_off(
    const int* __restrict__ csum, int* __restrict__ coff, int nch)
{
    if (threadIdx.x == 0 && blockIdx.x == 0) {
        int acc = 0;
        for (int i = 0; i < nch; ++i) { coff[i] = acc; acc += csum[i]; }
    }
}

// EXCLUSIVE scan of deg -> pos (start offsets), chunked
__global__ __launch_bounds__(256) void scan_within_excl(
    const int* __restrict__ deg, int* __restrict__ pos,
    const int* __restrict__ coff, int N)
{
    __shared__ int s[256];
    int t = threadIdx.x;
    int base = blockIdx.x * CHUNK + t * 4;
    int v0 = 0, v1 = 0, v2 = 0, v3 = 0;
    if (base + 0 < N) v0 = deg[base + 0];
    if (base + 1 < N) v1 = deg[base + 1];
    if (base + 2 < N) v2 = deg[base + 2];
    if (base + 3 < N) v3 = deg[base + 3];
    s[t] = v0 + v1 + v2 + v3;
    __syncthreads();
    for (int o = 1; o < 256; o <<= 1) {
        int add = (t >= o) ? s[t - o] : 0;
        __syncthreads();
        s[t] += add;
        __syncthreads();
    }
    int run = coff[blockIdx.x] + (t > 0 ? s[t - 1] : 0);
    if (base + 0 < N) pos[base + 0] = run; run += v0;
    if (base + 1 < N) pos[base + 1] = run; run += v1;
    if (base + 2 < N) pos[base + 2] = run; run += v2;
    if (base + 3 < N) pos[base + 3] = run;
}

// pass 2: atomic-free payload scatter; ea converted to fp16 (16 B/edge)
__global__ __launch_bounds__(256) void scatter_perm(
    const int* __restrict__ ei, const float* __restrict__ ea,
    const int* __restrict__ pos, const unsigned short* __restrict__ r,
    int* __restrict__ dst_perm, uint4* __restrict__ eap, int E)
{
    int e = blockIdx.x * 256 + threadIdx.x;
    if (e >= E) return;
    int s = ei[e];
    int d = ei[E + e];
    int p = pos[s] + (int)r[e];
    dst_perm[p] = d;
    float4 a0 = *(const float4*)(ea + (size_t)e * 8);
    float4 a1 = *(const float4*)(ea + (size_t)e * 8 + 4);
    uint4 u;
    u.x = pack2(a0.x, a0.y);
    u.y = pack2(a0.z, a0.w);
    u.z = pack2(a1.x, a1.y);
    u.w = pack2(a1.z, a1.w);
    eap[p] = u;
}

// ---------------------------------------------------------------------------
// conv1 (8 lanes/node) + fused hw-transform for conv2:
//   agg = segment_max(relu(relu(m@w1+b1)@w2+b2))  (clamped at 0 via init)
//   hw_s[n] = agg[n] @ cw1[0:16]  + cb1      (fp32, sequential consumer)
//   hw_d[n] = agg[n] @ cw1[16:32]            (fp16, random-gather consumer)
// ---------------------------------------------------------------------------
__global__ __launch_bounds__(256) void conv1_g8(
    const float* __restrict__ x,        // [N,4]
    const int*   __restrict__ dst_perm, // [E]
    const uint4* __restrict__ eap,      // [E] fp16x8
    const float* __restrict__ w1, const float* __restrict__ b1,
    const float* __restrict__ w2, const float* __restrict__ b2,
    const float* __restrict__ cw1, const float* __restrict__ cb1, // conv2 w1/b1
    const int*   __restrict__ pos,
    float* __restrict__ hw_s,           // [N,16] fp32
    unsigned short* __restrict__ hw_dh, // [N,16] fp16
    int N, int E)
{
    int tid = threadIdx.x;
    int n = blockIdx.x * 32 + (tid >> 3);
    if (n >= N) return;
    int g = tid & 7;
    int start = pos[n];
    int end = (n + 1 < N) ? pos[n + 1] : E;

    // loop-invariant src part: b1 + x[n] @ w1[0:4,:]
    float4 xs = *(const float4*)(x + (size_t)n * 4);
    float ts[16];
    #pragma unroll
    for (int j = 0; j < 16; ++j) ts[j] = b1[j];
    #pragma unroll
    for (int j = 0; j < 16; ++j) {
        ts[j] = fmaf(xs.x, w1[0 * 16 + j], ts[j]);
        ts[j] = fmaf(xs.y, w1[1 * 16 + j], ts[j]);
        ts[j] = fmaf(xs.z, w1[2 * 16 + j], ts[j]);
        ts[j] = fmaf(xs.w, w1[3 * 16 + j], ts[j]);
    }

    float acc[16];
    #pragma unroll
    for (int j = 0; j < 16; ++j) acc[j] = 0.0f;

    for (int k = start + g; k < end; k += 8) {
        int dst = dst_perm[k];
        float4 xd = *(const float4*)(x + (size_t)dst * 4);
        uint4 u = eap[k];
        float ae[8];
        { float2 f = unpack2(u.x); ae[0] = f.x; ae[1] = f.y; }
        { float2 f = unpack2(u.y); ae[2] = f.x; ae[3] = f.y; }
        { float2 f = unpack2(u.z); ae[4] = f.x; ae[5] = f.y; }
        { float2 f = unpack2(u.w); ae[6] = f.x; ae[7] = f.y; }

        float t[16];
        #pragma unroll
        for (int j = 0; j < 16; ++j) {
            float v = ts[j];
            v = fmaf(xd.x, w1[4 * 16 + j], v);
            v = fmaf(xd.y, w1[5 * 16 + j], v);
            v = fmaf(xd.z, w1[6 * 16 + j], v);
            v = fmaf(xd.w, w1[7 * 16 + j], v);
            #pragma unroll
            for (int kk = 0; kk < 8; ++kk)
                v = fmaf(ae[kk], w1[(8 + kk) * 16 + j], v);
            t[j] = fmaxf(v, 0.0f);
        }

        float o[16];
        #pragma unroll
        for (int j = 0; j < 16; ++j) o[j] = b2[j];
        #pragma unroll
        for (int kk = 0; kk < 16; ++kk) {
            float tk = t[kk];
            #pragma unroll
            for (int j = 0; j < 16; ++j) o[j] = fmaf(tk, w2[kk * 16 + j], o[j]);
        }
        #pragma unroll
        for (int j = 0; j < 16; ++j) acc[j] = fmaxf(acc[j], o[j]);
    }

    // butterfly max: afterwards every lane of the group holds full acc
    #pragma unroll
    for (int mask = 1; mask < 8; mask <<= 1) {
        #pragma unroll
        for (int j = 0; j < 16; ++j)
            acc[j] = fmaxf(acc[j], __shfl_xor(acc[j], mask, 64));
    }

    // fused transform: lane g computes channels j0=2g, j1=2g+1
    int j0 = 2 * g, j1 = 2 * g + 1;
    float hs0 = cb1[j0], hs1 = cb1[j1], hd0 = 0.0f, hd1 = 0.0f;
    #pragma unroll
    for (int k = 0; k < 16; ++k) {
        float ak = acc[k];
        hs0 = fmaf(ak, cw1[k * 16 + j0], hs0);
        hs1 = fmaf(ak, cw1[k * 16 + j1], hs1);
        hd0 = fmaf(ak, cw1[(16 + k) * 16 + j0], hd0);
        hd1 = fmaf(ak, cw1[(16 + k) * 16 + j1], hd1);
    }
    *(float2*)(hw_s + (size_t)n * 16 + j0) = make_float2(hs0, hs1);
    ((unsigned int*)hw_dh)[(size_t)n * 8 + g] = pack2(hd0, hd1);
}

// ---------------------------------------------------------------------------
// conv2 + head fused: 8 lanes per node, precomputed hw_s(f32)/hw_d(f16)
// ---------------------------------------------------------------------------
__global__ __launch_bounds__(256) void conv2_g8_head(
    const float* __restrict__ hw_s,           // [N,16] fp32 (+b1 folded)
    const unsigned short* __restrict__ hw_dh, // [N,16] fp16
    const int*   __restrict__ dst_perm,
    const uint4* __restrict__ eap,
    const float* __restrict__ w1,             // [40,16] rows 32:40 used
    const float* __restrict__ w2, const float* __restrict__ b2,
    const float* __restrict__ l1w, const float* __restrict__ l1b,
    const float* __restrict__ l2w, const float* __restrict__ l2b,
    const int*   __restrict__ pos,
    float* __restrict__ out, int N, int E)
{
    int tid = threadIdx.x;
    int n = blockIdx.x * 32 + (tid >> 3);
    if (n >= N) return;
    int g = tid & 7;
    int start = pos[n];
    int end = (n + 1 < N) ? pos[n + 1] : E;

    float ts[16];
    #pragma unroll
    for (int q = 0; q < 4; ++q) {
        float4 v = *(const float4*)(hw_s + (size_t)n * 16 + q * 4);
        ts[q*4+0] = v.x; ts[q*4+1] = v.y; ts[q*4+2] = v.z; ts[q*4+3] = v.w;
    }

    float acc[16];
    #pragma unroll
    for (int j = 0; j < 16; ++j) acc[j] = 0.0f;

    for (int k = start + g; k < end; k += 8) {
        int dst = dst_perm[k];
        uint4 u = eap[k];
        float ae[8];
        { float2 f = unpack2(u.x); ae[0] = f.x; ae[1] = f.y; }
        { float2 f = unpack2(u.y); ae[2] = f.x; ae[3] = f.y; }
        { float2 f = unpack2(u.z); ae[4] = f.x; ae[5] = f.y; }
        { float2 f = unpack2(u.w); ae[6] = f.x; ae[7] = f.y; }

        const unsigned short* hb = hw_dh + (size_t)dst * 16;
        uint4 u0 = *(const uint4*)(hb);
        uint4 u1 = *(const uint4*)(hb + 8);
        float hd[16];
        { float2 f = unpack2(u0.x); hd[0] = f.x; hd[1] = f.y; }
        { float2 f = unpack2(u0.y); hd[2] = f.x; hd[3] = f.y; }
        { float2 f = unpack2(u0.z); hd[4] = f.x; hd[5] = f.y; }
        { float2 f = unpack2(u0.w); hd[6] = f.x; hd[7] = f.y; }
        { float2 f = unpack2(u1.x); hd[8] = f.x; hd[9] = f.y; }
        { float2 f = unpack2(u1.y); hd[10] = f.x; hd[11] = f.y; }
        { float2 f = unpack2(u1.z); hd[12] = f.x; hd[13] = f.y; }
        { float2 f = unpack2(u1.w); hd[14] = f.x; hd[15] = f.y; }

        float t[16];
        #pragma unroll
        for (int j = 0; j < 16; ++j) {
            float v = ts[j] + hd[j];
            #pragma unroll
            for (int kk = 0; kk < 8; ++kk)
                v = fmaf(ae[kk], w1[(32 + kk) * 16 + j], v);
            t[j] = fmaxf(v, 0.0f);
        }

        float o[16];
        #pragma unroll
        for (int j = 0; j < 16; ++j) o[j] = b2[j];
        #pragma unroll
        for (int kk = 0; kk < 16; ++kk) {
            float tk = t[kk];
            #pragma unroll
            for (int j = 0; j < 16; ++j) o[j] = fmaf(tk, w2[kk * 16 + j], o[j]);
        }
        #pragma unroll
        for (int j = 0; j < 16; ++j) acc[j] = fmaxf(acc[j], o[j]);
    }

    #pragma unroll
    for (int mask = 1; mask < 8; mask <<= 1) {
        #pragma unroll
        for (int j = 0; j < 16; ++j)
            acc[j] = fmaxf(acc[j], __shfl_xor(acc[j], mask, 64));
    }

    // head: relu(acc @ l1w + l1b) @ l2w + l2b  (lane 0 stores)
    float t2[16];
    #pragma unroll
    for (int j = 0; j < 16; ++j) t2[j] = l1b[j];
    #pragma unroll
    for (int kk = 0; kk < 16; ++kk) {
        float ak = acc[kk];
        #pragma unroll
        for (int j = 0; j < 16; ++j) t2[j] = fmaf(ak, l1w[kk * 16 + j], t2[j]);
    }
    float r = l2b[0];
    #pragma unroll
    for (int j = 0; j < 16; ++j) r = fmaf(fmaxf(t2[j], 0.0f), l2w[j], r);
    if (g == 0) out[n] = r;
}

// ===========================================================================
extern "C" void kernel_launch(void* const* d_in, const int* in_sizes, int n_in,
                              void* d_out, int out_size, void* d_ws, size_t ws_size,
                              hipStream_t stream)
{
    const float* x     = (const float*)d_in[0];
    const int*   ei    = (const int*)  d_in[1];
    const float* ea    = (const float*)d_in[2];
    const float* c1_w1 = (const float*)d_in[3];
    const float* c1_b1 = (const float*)d_in[4];
    const float* c1_w2 = (const float*)d_in[5];
    const float* c1_b2 = (const float*)d_in[6];
    const float* c2_w1 = (const float*)d_in[7];
    const float* c2_b1 = (const float*)d_in[8];
    const float* c2_w2 = (const float*)d_in[9];
    const float* c2_b2 = (const float*)d_in[10];
    const float* l1_w  = (const float*)d_in[11];
    const float* l1_b  = (const float*)d_in[12];
    const float* l2_w  = (const float*)d_in[13];
    const float* l2_b  = (const float*)d_in[14];
    float* out = (float*)d_out;

    const int N = in_sizes[0] / 4;   // 100000
    const int E = in_sizes[2] / 8;   // 1600000
    const int nch = (N + CHUNK - 1) / CHUNK;

    const int BLK = 256;
    const int egrid = (E + BLK - 1) / BLK;
    const int ggrid = (N + 31) / 32;       // 8 lanes/node, 32 nodes/block

    // ---- workspace layout (16B-aligned pieces), total ~46 MB ----
    size_t szN16f = (size_t)N * 16 * 4;                    // 6.4 MB
    size_t szN16h = (size_t)N * 16 * 2;                    // 3.2 MB
    size_t szN    = ((size_t)N * 4 + 15) & ~(size_t)15;
    size_t szNh   = ((size_t)N * 2 + 15) & ~(size_t)15;    // (unused granularity helper)
    size_t szEh   = ((size_t)E * 2 + 15) & ~(size_t)15;    // r uint16
    size_t szE4   = (size_t)E * 4;
    size_t szE16  = (size_t)E * 16;                        // eap fp16x8
    (void)szNh;

    size_t hws_off  = 0;
    size_t hwdh_off = hws_off  + szN16f;
    size_t deg_off  = hwdh_off + szN16h;
    size_t pos_off  = deg_off  + szN;
    size_t r_off    = pos_off  + szN;
    size_t dstp_off = r_off    + szEh;
    size_t eap_off  = dstp_off + szE4;
    size_t cs_off   = eap_off  + szE16;
    size_t cf_off   = cs_off   + 4096;

    float*          hw_s = (float*)((char*)d_ws + hws_off);
    unsigned short* hwdh = (unsigned short*)((char*)d_ws + hwdh_off);
    int*            deg  = (int*)  ((char*)d_ws + deg_off);
    int*            pos  = (int*)  ((char*)d_ws + pos_off);
    unsigned short* r    = (unsigned short*)((char*)d_ws + r_off);
    int*            dstp = (int*)  ((char*)d_ws + dstp_off);
    uint4*          eap  = (uint4*)((char*)d_ws + eap_off);
    int*            csum = (int*)  ((char*)d_ws + cs_off);
    int*            coff = (int*)  ((char*)d_ws + cf_off);

    hipMemsetAsync(deg, 0, (size_t)N * 4, stream);
    rank_kernel<<<egrid, BLK, 0, stream>>>(ei, deg, r, E);
    scan_chunk_sums<<<nch, BLK, 0, stream>>>(deg, csum, N);
    scan_chunk_off<<<1, 64, 0, stream>>>(csum, coff, nch);
    scan_within_excl<<<nch, BLK, 0, stream>>>(deg, pos, coff, N);
    scatter_perm<<<egrid, BLK, 0, stream>>>(ei, ea, pos, r, dstp, eap, E);
    conv1_g8<<<ggrid, BLK, 0, stream>>>(x, dstp, eap, c1_w1, c1_b1, c1_w2, c1_b2,
                                        c2_w1, c2_b1, pos, hw_s, hwdh, N, E);
    conv2_g8_head<<<ggrid, BLK, 0, stream>>>(hw_s, hwdh, dstp, eap,
                                             c2_w1, c2_w2, c2_b2,
                                             l1_w, l1_b, l2_w, l2_b,
                                             pos, out, N, E);
}

// Round 5
// 394.000 us; speedup vs baseline: 5.4508x; 1.1246x over previous
//
#include <hip/hip_runtime.h>
#include <hip/hip_fp16.h>

#define CHUNK 1024

typedef _Float16 half8 __attribute__((ext_vector_type(8)));
typedef float floatx4 __attribute__((ext_vector_type(4)));

__device__ __forceinline__ unsigned int pack2(float a, float b) {
    __half2 h = __floats2half2_rn(a, b);
    return *(unsigned int*)&h;
}
__device__ __forceinline__ float2 unpack2(unsigned int u) {
    __half2 h = *(__half2*)&u;
    return __half22float2(h);
}

// ===========================================================================
// CSR build: edges grouped by src; payload (src, dst, ea-fp16) permuted.
// ===========================================================================
__global__ __launch_bounds__(256) void rank_kernel(
    const int* __restrict__ ei, int* __restrict__ deg,
    unsigned short* __restrict__ r, int E)
{
    int e = blockIdx.x * 256 + threadIdx.x;
    if (e < E) r[e] = (unsigned short)atomicAdd(&deg[ei[e]], 1);
}

__global__ __launch_bounds__(256) void scan_chunk_sums(
    const int* __restrict__ v, int* __restrict__ csum, int N)
{
    __shared__ int s[256];
    int base = blockIdx.x * CHUNK;
    int t = threadIdx.x;
    int acc = 0;
    #pragma unroll
    for (int i = 0; i < CHUNK / 256; ++i) {
        int idx = base + t + i * 256;
        if (idx < N) acc += v[idx];
    }
    s[t] = acc; __syncthreads();
    for (int o = 128; o > 0; o >>= 1) {
        if (t < o) s[t] += s[t + o];
        __syncthreads();
    }
    if (t == 0) csum[blockIdx.x] = s[0];
}

__global__ void scan_chunk_off(
    const int* __restrict__ csum, int* __restrict__ coff, int nch)
{
    if (threadIdx.x == 0 && blockIdx.x == 0) {
        int acc = 0;
        for (int i = 0; i < nch; ++i) { coff[i] = acc; acc += csum[i]; }
    }
}

__global__ __launch_bounds__(256) void scan_within_excl(
    const int* __restrict__ deg, int* __restrict__ pos,
    const int* __restrict__ coff, int N)
{
    __shared__ int s[256];
    int t = threadIdx.x;
    int base = blockIdx.x * CHUNK + t * 4;
    int v0 = 0, v1 = 0, v2 = 0, v3 = 0;
    if (base + 0 < N) v0 = deg[base + 0];
    if (base + 1 < N) v1 = deg[base + 1];
    if (base + 2 < N) v2 = deg[base + 2];
    if (base + 3 < N) v3 = deg[base + 3];
    s[t] = v0 + v1 + v2 + v3;
    __syncthreads();
    for (int o = 1; o < 256; o <<= 1) {
        int add = (t >= o) ? s[t - o] : 0;
        __syncthreads();
        s[t] += add;
        __syncthreads();
    }
    int run = coff[blockIdx.x] + (t > 0 ? s[t - 1] : 0);
    if (base + 0 < N) pos[base + 0] = run; run += v0;
    if (base + 1 < N) pos[base + 1] = run; run += v1;
    if (base + 2 < N) pos[base + 2] = run; run += v2;
    if (base + 3 < N) pos[base + 3] = run;
}

__global__ __launch_bounds__(256) void scatter_perm(
    const int* __restrict__ ei, const float* __restrict__ ea,
    const int* __restrict__ pos, const unsigned short* __restrict__ r,
    int* __restrict__ src_perm, int* __restrict__ dst_perm,
    uint4* __restrict__ eap, int E)
{
    int e = blockIdx.x * 256 + threadIdx.x;
    if (e >= E) return;
    int s = ei[e];
    int d = ei[E + e];
    int p = pos[s] + (int)r[e];
    src_perm[p] = s;
    dst_perm[p] = d;
    float4 a0 = *(const float4*)(ea + (size_t)e * 8);
    float4 a1 = *(const float4*)(ea + (size_t)e * 8 + 4);
    uint4 u;
    u.x = pack2(a0.x, a0.y);
    u.y = pack2(a0.z, a0.w);
    u.z = pack2(a1.x, a1.y);
    u.w = pack2(a1.z, a1.w);
    eap[p] = u;
}

// ===========================================================================
// MFMA edge-MLP kernels. Per wave: a 16-edge tile.
//   layouts (gfx950, 16x16x32): A[m=lane&15][k=8q+j], B[k=8q+j][n=lane&15],
//   C/D: col=lane&15, row=4q+reg. K padded 32 (q>=2 fragments zero).
// ===========================================================================
__global__ __launch_bounds__(256) void edge_mlp1(
    const float* __restrict__ x,          // [N,4]
    const int*   __restrict__ srcp,       // [E]
    const int*   __restrict__ dstp,       // [E]
    const _Float16* __restrict__ eap,     // [E,8]
    const float* __restrict__ w1, const float* __restrict__ b1,  // 16x16
    const float* __restrict__ w2, const float* __restrict__ b2,  // 16x16
    _Float16* __restrict__ m2h,           // [E,16]
    int E)
{
    __shared__ float    lsf[4][16][20];
    __shared__ _Float16 lsh[4][16][20];
    int lane = threadIdx.x & 63;
    int w    = threadIdx.x >> 6;
    int e16  = lane & 15, q = lane >> 4;
    int wgid = blockIdx.x * 4 + w;
    int nw   = gridDim.x * 4;
    int ntiles = (E + 15) >> 4;

    half8 B1, B2;
    #pragma unroll
    for (int j = 0; j < 8; ++j) { B1[j] = (_Float16)0.f; B2[j] = (_Float16)0.f; }
    if (q < 2) {
        #pragma unroll
        for (int j = 0; j < 8; ++j) {
            B1[j] = (_Float16)w1[(8 * q + j) * 16 + e16];
            B2[j] = (_Float16)w2[(8 * q + j) * 16 + e16];
        }
    }
    float b1c = b1[e16], b2c = b2[e16];

    for (int tile = wgid; tile < ntiles; tile += nw) {
        int ebase = tile << 4;
        int e = ebase + e16;

        half8 A;
        #pragma unroll
        for (int j = 0; j < 8; ++j) A[j] = (_Float16)0.f;
        if (q == 0 && e < E) {
            int s = srcp[e], d = dstp[e];
            float4 xs = *(const float4*)(x + (size_t)s * 4);
            float4 xd = *(const float4*)(x + (size_t)d * 4);
            A[0] = (_Float16)xs.x; A[1] = (_Float16)xs.y;
            A[2] = (_Float16)xs.z; A[3] = (_Float16)xs.w;
            A[4] = (_Float16)xd.x; A[5] = (_Float16)xd.y;
            A[6] = (_Float16)xd.z; A[7] = (_Float16)xd.w;
        } else if (q == 1 && e < E) {
            A = *(const half8*)(eap + (size_t)e * 8);
        }

        floatx4 C = {b1c, b1c, b1c, b1c};
        C = __builtin_amdgcn_mfma_f32_16x16x32_f16(A, B1, C, 0, 0, 0);
        #pragma unroll
        for (int i = 0; i < 4; ++i)
            lsf[w][4 * q + i][e16] = fmaxf(C[i], 0.0f);
        __builtin_amdgcn_wave_barrier();

        half8 A2;
        #pragma unroll
        for (int j = 0; j < 8; ++j) A2[j] = (_Float16)0.f;
        if (q < 2) {
            #pragma unroll
            for (int j = 0; j < 8; ++j)
                A2[j] = (_Float16)lsf[w][e16][8 * q + j];
        }
        floatx4 C2 = {b2c, b2c, b2c, b2c};
        C2 = __builtin_amdgcn_mfma_f32_16x16x32_f16(A2, B2, C2, 0, 0, 0);
        __builtin_amdgcn_wave_barrier();
        #pragma unroll
        for (int i = 0; i < 4; ++i)
            lsh[w][4 * q + i][e16] = (_Float16)C2[i];
        __builtin_amdgcn_wave_barrier();
        if (e < E) {
            uint2 v = *(uint2*)&lsh[w][e16][4 * q];
            *(uint2*)(m2h + (size_t)e * 16 + 4 * q) = v;
        }
    }
}

__global__ __launch_bounds__(256) void edge_mlp2(
    const float* __restrict__ hw_s,            // [N,16] fp32 (cb1 folded)
    const unsigned short* __restrict__ hw_dh,  // [N,16] fp16
    const int*   __restrict__ srcp,
    const int*   __restrict__ dstp,
    const _Float16* __restrict__ eap,
    const float* __restrict__ w1,              // [40,16] rows 32:40
    const float* __restrict__ w2, const float* __restrict__ b2,
    _Float16* __restrict__ m2h, int E)
{
    __shared__ float    lsf[4][16][20];
    __shared__ _Float16 lsh[4][16][20];
    int lane = threadIdx.x & 63;
    int w    = threadIdx.x >> 6;
    int e16  = lane & 15, q = lane >> 4;
    int wgid = blockIdx.x * 4 + w;
    int nw   = gridDim.x * 4;
    int ntiles = (E + 15) >> 4;
    const __half* hwd = (const __half*)hw_dh;

    half8 B1, B2;
    #pragma unroll
    for (int j = 0; j < 8; ++j) { B1[j] = (_Float16)0.f; B2[j] = (_Float16)0.f; }
    if (q == 0) {
        #pragma unroll
        for (int j = 0; j < 8; ++j)
            B1[j] = (_Float16)w1[(32 + j) * 16 + e16];
    }
    if (q < 2) {
        #pragma unroll
        for (int j = 0; j < 8; ++j)
            B2[j] = (_Float16)w2[(8 * q + j) * 16 + e16];
    }
    float b2c = b2[e16];

    for (int tile = wgid; tile < ntiles; tile += nw) {
        int ebase = tile << 4;
        int e = ebase + e16;

        half8 A;
        #pragma unroll
        for (int j = 0; j < 8; ++j) A[j] = (_Float16)0.f;
        if (q == 0 && e < E)
            A = *(const half8*)(eap + (size_t)e * 8);

        // C init: ts[src[row]] + hd[dst[row]] per (row=4q+i, col=e16)
        floatx4 C;
        #pragma unroll
        for (int i = 0; i < 4; ++i) {
            int rr = ebase + 4 * q + i;
            float v = 0.0f;
            if (rr < E) {
                int s = srcp[rr], d = dstp[rr];
                v = hw_s[(size_t)s * 16 + e16]
                  + __half2float(hwd[(size_t)d * 16 + e16]);
            }
            C[i] = v;
        }
        C = __builtin_amdgcn_mfma_f32_16x16x32_f16(A, B1, C, 0, 0, 0);
        #pragma unroll
        for (int i = 0; i < 4; ++i)
            lsf[w][4 * q + i][e16] = fmaxf(C[i], 0.0f);
        __builtin_amdgcn_wave_barrier();

        half8 A2;
        #pragma unroll
        for (int j = 0; j < 8; ++j) A2[j] = (_Float16)0.f;
        if (q < 2) {
            #pragma unroll
            for (int j = 0; j < 8; ++j)
                A2[j] = (_Float16)lsf[w][e16][8 * q + j];
        }
        floatx4 C2 = {b2c, b2c, b2c, b2c};
        C2 = __builtin_amdgcn_mfma_f32_16x16x32_f16(A2, B2, C2, 0, 0, 0);
        __builtin_amdgcn_wave_barrier();
        #pragma unroll
        for (int i = 0; i < 4; ++i)
            lsh[w][4 * q + i][e16] = (_Float16)C2[i];
        __builtin_amdgcn_wave_barrier();
        if (e < E) {
            uint2 v = *(uint2*)&lsh[w][e16][4 * q];
            *(uint2*)(m2h + (size_t)e * 16 + 4 * q) = v;
        }
    }
}

// ===========================================================================
// Streaming segment-max kernels (8 lanes/node) + fused epilogues.
// ===========================================================================
__global__ __launch_bounds__(256) void segmax1_hw(
    const _Float16* __restrict__ m2h, const int* __restrict__ pos,
    const float* __restrict__ cw1, const float* __restrict__ cb1, // conv2 w1/b1
    float* __restrict__ hw_s, unsigned short* __restrict__ hw_dh,
    int N, int E)
{
    int tid = threadIdx.x;
    int n = blockIdx.x * 32 + (tid >> 3);
    if (n >= N) return;
    int g = tid & 7;
    int start = pos[n];
    int end = (n + 1 < N) ? pos[n + 1] : E;

    float acc[16];
    #pragma unroll
    for (int j = 0; j < 16; ++j) acc[j] = 0.0f;

    for (int k = start + g; k < end; k += 8) {
        uint4 u0 = *(const uint4*)(m2h + (size_t)k * 16);
        uint4 u1 = *(const uint4*)(m2h + (size_t)k * 16 + 8);
        float2 f;
        f = unpack2(u0.x); acc[0]  = fmaxf(acc[0],  f.x); acc[1]  = fmaxf(acc[1],  f.y);
        f = unpack2(u0.y); acc[2]  = fmaxf(acc[2],  f.x); acc[3]  = fmaxf(acc[3],  f.y);
        f = unpack2(u0.z); acc[4]  = fmaxf(acc[4],  f.x); acc[5]  = fmaxf(acc[5],  f.y);
        f = unpack2(u0.w); acc[6]  = fmaxf(acc[6],  f.x); acc[7]  = fmaxf(acc[7],  f.y);
        f = unpack2(u1.x); acc[8]  = fmaxf(acc[8],  f.x); acc[9]  = fmaxf(acc[9],  f.y);
        f = unpack2(u1.y); acc[10] = fmaxf(acc[10], f.x); acc[11] = fmaxf(acc[11], f.y);
        f = unpack2(u1.z); acc[12] = fmaxf(acc[12], f.x); acc[13] = fmaxf(acc[13], f.y);
        f = unpack2(u1.w); acc[14] = fmaxf(acc[14], f.x); acc[15] = fmaxf(acc[15], f.y);
    }
    #pragma unroll
    for (int mask = 1; mask < 8; mask <<= 1) {
        #pragma unroll
        for (int j = 0; j < 16; ++j)
            acc[j] = fmaxf(acc[j], __shfl_xor(acc[j], mask, 64));
    }

    int j0 = 2 * g, j1 = 2 * g + 1;
    float hs0 = cb1[j0], hs1 = cb1[j1], hd0 = 0.0f, hd1 = 0.0f;
    #pragma unroll
    for (int k = 0; k < 16; ++k) {
        float ak = acc[k];
        hs0 = fmaf(ak, cw1[k * 16 + j0], hs0);
        hs1 = fmaf(ak, cw1[k * 16 + j1], hs1);
        hd0 = fmaf(ak, cw1[(16 + k) * 16 + j0], hd0);
        hd1 = fmaf(ak, cw1[(16 + k) * 16 + j1], hd1);
    }
    *(float2*)(hw_s + (size_t)n * 16 + j0) = make_float2(hs0, hs1);
    ((unsigned int*)hw_dh)[(size_t)n * 8 + g] = pack2(hd0, hd1);
}

__global__ __launch_bounds__(256) void segmax2_head(
    const _Float16* __restrict__ m2h, const int* __restrict__ pos,
    const float* __restrict__ l1w, const float* __restrict__ l1b,
    const float* __restrict__ l2w, const float* __restrict__ l2b,
    float* __restrict__ out, int N, int E)
{
    int tid = threadIdx.x;
    int n = blockIdx.x * 32 + (tid >> 3);
    if (n >= N) return;
    int g = tid & 7;
    int start = pos[n];
    int end = (n + 1 < N) ? pos[n + 1] : E;

    float acc[16];
    #pragma unroll
    for (int j = 0; j < 16; ++j) acc[j] = 0.0f;

    for (int k = start + g; k < end; k += 8) {
        uint4 u0 = *(const uint4*)(m2h + (size_t)k * 16);
        uint4 u1 = *(const uint4*)(m2h + (size_t)k * 16 + 8);
        float2 f;
        f = unpack2(u0.x); acc[0]  = fmaxf(acc[0],  f.x); acc[1]  = fmaxf(acc[1],  f.y);
        f = unpack2(u0.y); acc[2]  = fmaxf(acc[2],  f.x); acc[3]  = fmaxf(acc[3],  f.y);
        f = unpack2(u0.z); acc[4]  = fmaxf(acc[4],  f.x); acc[5]  = fmaxf(acc[5],  f.y);
        f = unpack2(u0.w); acc[6]  = fmaxf(acc[6],  f.x); acc[7]  = fmaxf(acc[7],  f.y);
        f = unpack2(u1.x); acc[8]  = fmaxf(acc[8],  f.x); acc[9]  = fmaxf(acc[9],  f.y);
        f = unpack2(u1.y); acc[10] = fmaxf(acc[10], f.x); acc[11] = fmaxf(acc[11], f.y);
        f = unpack2(u1.z); acc[12] = fmaxf(acc[12], f.x); acc[13] = fmaxf(acc[13], f.y);
        f = unpack2(u1.w); acc[14] = fmaxf(acc[14], f.x); acc[15] = fmaxf(acc[15], f.y);
    }
    #pragma unroll
    for (int mask = 1; mask < 8; mask <<= 1) {
        #pragma unroll
        for (int j = 0; j < 16; ++j)
            acc[j] = fmaxf(acc[j], __shfl_xor(acc[j], mask, 64));
    }

    float t2[16];
    #pragma unroll
    for (int j = 0; j < 16; ++j) t2[j] = l1b[j];
    #pragma unroll
    for (int kk = 0; kk < 16; ++kk) {
        float ak = acc[kk];
        #pragma unroll
        for (int j = 0; j < 16; ++j) t2[j] = fmaf(ak, l1w[kk * 16 + j], t2[j]);
    }
    float r = l2b[0];
    #pragma unroll
    for (int j = 0; j < 16; ++j) r = fmaf(fmaxf(t2[j], 0.0f), l2w[j], r);
    if (g == 0) out[n] = r;
}

// ===========================================================================
// Tier-B fallback (round-4 VALU conv kernels), used if ws < ~100 MB.
// ===========================================================================
__global__ __launch_bounds__(256) void conv1_g8(
    const float* __restrict__ x, const int* __restrict__ dst_perm,
    const uint4* __restrict__ eap,
    const float* __restrict__ w1, const float* __restrict__ b1,
    const float* __restrict__ w2, const float* __restrict__ b2,
    const float* __restrict__ cw1, const float* __restrict__ cb1,
    const int* __restrict__ pos,
    float* __restrict__ hw_s, unsigned short* __restrict__ hw_dh,
    int N, int E)
{
    int tid = threadIdx.x;
    int n = blockIdx.x * 32 + (tid >> 3);
    if (n >= N) return;
    int g = tid & 7;
    int start = pos[n];
    int end = (n + 1 < N) ? pos[n + 1] : E;

    float4 xs = *(const float4*)(x + (size_t)n * 4);
    float ts[16];
    #pragma unroll
    for (int j = 0; j < 16; ++j) ts[j] = b1[j];
    #pragma unroll
    for (int j = 0; j < 16; ++j) {
        ts[j] = fmaf(xs.x, w1[0 * 16 + j], ts[j]);
        ts[j] = fmaf(xs.y, w1[1 * 16 + j], ts[j]);
        ts[j] = fmaf(xs.z, w1[2 * 16 + j], ts[j]);
        ts[j] = fmaf(xs.w, w1[3 * 16 + j], ts[j]);
    }
    float acc[16];
    #pragma unroll
    for (int j = 0; j < 16; ++j) acc[j] = 0.0f;

    for (int k = start + g; k < end; k += 8) {
        int dst = dst_perm[k];
        float4 xd = *(const float4*)(x + (size_t)dst * 4);
        uint4 u = eap[k];
        float ae[8];
        { float2 f = unpack2(u.x); ae[0] = f.x; ae[1] = f.y; }
        { float2 f = unpack2(u.y); ae[2] = f.x; ae[3] = f.y; }
        { float2 f = unpack2(u.z); ae[4] = f.x; ae[5] = f.y; }
        { float2 f = unpack2(u.w); ae[6] = f.x; ae[7] = f.y; }
        float t[16];
        #pragma unroll
        for (int j = 0; j < 16; ++j) {
            float v = ts[j];
            v = fmaf(xd.x, w1[4 * 16 + j], v);
            v = fmaf(xd.y, w1[5 * 16 + j], v);
            v = fmaf(xd.z, w1[6 * 16 + j], v);
            v = fmaf(xd.w, w1[7 * 16 + j], v);
            #pragma unroll
            for (int kk = 0; kk < 8; ++kk)
                v = fmaf(ae[kk], w1[(8 + kk) * 16 + j], v);
            t[j] = fmaxf(v, 0.0f);
        }
        float o[16];
        #pragma unroll
        for (int j = 0; j < 16; ++j) o[j] = b2[j];
        #pragma unroll
        for (int kk = 0; kk < 16; ++kk) {
            float tk = t[kk];
            #pragma unroll
            for (int j = 0; j < 16; ++j) o[j] = fmaf(tk, w2[kk * 16 + j], o[j]);
        }
        #pragma unroll
        for (int j = 0; j < 16; ++j) acc[j] = fmaxf(acc[j], o[j]);
    }
    #pragma unroll
    for (int mask = 1; mask < 8; mask <<= 1) {
        #pragma unroll
        for (int j = 0; j < 16; ++j)
            acc[j] = fmaxf(acc[j], __shfl_xor(acc[j], mask, 64));
    }
    int j0 = 2 * g, j1 = 2 * g + 1;
    float hs0 = cb1[j0], hs1 = cb1[j1], hd0 = 0.0f, hd1 = 0.0f;
    #pragma unroll
    for (int k = 0; k < 16; ++k) {
        float ak = acc[k];
        hs0 = fmaf(ak, cw1[k * 16 + j0], hs0);
        hs1 = fmaf(ak, cw1[k * 16 + j1], hs1);
        hd0 = fmaf(ak, cw1[(16 + k) * 16 + j0], hd0);
        hd1 = fmaf(ak, cw1[(16 + k) * 16 + j1], hd1);
    }
    *(float2*)(hw_s + (size_t)n * 16 + j0) = make_float2(hs0, hs1);
    ((unsigned int*)hw_dh)[(size_t)n * 8 + g] = pack2(hd0, hd1);
}

__global__ __launch_bounds__(256) void conv2_g8_head(
    const float* __restrict__ hw_s, const unsigned short* __restrict__ hw_dh,
    const int* __restrict__ dst_perm, const uint4* __restrict__ eap,
    const float* __restrict__ w1,
    const float* __restrict__ w2, const float* __restrict__ b2,
    const float* __restrict__ l1w, const float* __restrict__ l1b,
    const float* __restrict__ l2w, const float* __restrict__ l2b,
    const int* __restrict__ pos,
    float* __restrict__ out, int N, int E)
{
    int tid = threadIdx.x;
    int n = blockIdx.x * 32 + (tid >> 3);
    if (n >= N) return;
    int g = tid & 7;
    int start = pos[n];
    int end = (n + 1 < N) ? pos[n + 1] : E;

    float ts[16];
    #pragma unroll
    for (int q = 0; q < 4; ++q) {
        float4 v = *(const float4*)(hw_s + (size_t)n * 16 + q * 4);
        ts[q*4+0] = v.x; ts[q*4+1] = v.y; ts[q*4+2] = v.z; ts[q*4+3] = v.w;
    }
    float acc[16];
    #pragma unroll
    for (int j = 0; j < 16; ++j) acc[j] = 0.0f;

    for (int k = start + g; k < end; k += 8) {
        int dst = dst_perm[k];
        uint4 u = eap[k];
        float ae[8];
        { float2 f = unpack2(u.x); ae[0] = f.x; ae[1] = f.y; }
        { float2 f = unpack2(u.y); ae[2] = f.x; ae[3] = f.y; }
        { float2 f = unpack2(u.z); ae[4] = f.x; ae[5] = f.y; }
        { float2 f = unpack2(u.w); ae[6] = f.x; ae[7] = f.y; }
        const unsigned short* hb = hw_dh + (size_t)dst * 16;
        uint4 u0 = *(const uint4*)(hb);
        uint4 u1 = *(const uint4*)(hb + 8);
        float hd[16];
        { float2 f = unpack2(u0.x); hd[0] = f.x; hd[1] = f.y; }
        { float2 f = unpack2(u0.y); hd[2] = f.x; hd[3] = f.y; }
        { float2 f = unpack2(u0.z); hd[4] = f.x; hd[5] = f.y; }
        { float2 f = unpack2(u0.w); hd[6] = f.x; hd[7] = f.y; }
        { float2 f = unpack2(u1.x); hd[8] = f.x; hd[9] = f.y; }
        { float2 f = unpack2(u1.y); hd[10] = f.x; hd[11] = f.y; }
        { float2 f = unpack2(u1.z); hd[12] = f.x; hd[13] = f.y; }
        { float2 f = unpack2(u1.w); hd[14] = f.x; hd[15] = f.y; }
        float t[16];
        #pragma unroll
        for (int j = 0; j < 16; ++j) {
            float v = ts[j] + hd[j];
            #pragma unroll
            for (int kk = 0; kk < 8; ++kk)
                v = fmaf(ae[kk], w1[(32 + kk) * 16 + j], v);
            t[j] = fmaxf(v, 0.0f);
        }
        float o[16];
        #pragma unroll
        for (int j = 0; j < 16; ++j) o[j] = b2[j];
        #pragma unroll
        for (int kk = 0; kk < 16; ++kk) {
            float tk = t[kk];
            #pragma unroll
            for (int j = 0; j < 16; ++j) o[j] = fmaf(tk, w2[kk * 16 + j], o[j]);
        }
        #pragma unroll
        for (int j = 0; j < 16; ++j) acc[j] = fmaxf(acc[j], o[j]);
    }
    #pragma unroll
    for (int mask = 1; mask < 8; mask <<= 1) {
        #pragma unroll
        for (int j = 0; j < 16; ++j)
            acc[j] = fmaxf(acc[j], __shfl_xor(acc[j], mask, 64));
    }
    float t2[16];
    #pragma unroll
    for (int j = 0; j < 16; ++j) t2[j] = l1b[j];
    #pragma unroll
    for (int kk = 0; kk < 16; ++kk) {
        float ak = acc[kk];
        #pragma unroll
        for (int j = 0; j < 16; ++j) t2[j] = fmaf(ak, l1w[kk * 16 + j], t2[j]);
    }
    float r = l2b[0];
    #pragma unroll
    for (int j = 0; j < 16; ++j) r = fmaf(fmaxf(t2[j], 0.0f), l2w[j], r);
    if (g == 0) out[n] = r;
}

// ===========================================================================
extern "C" void kernel_launch(void* const* d_in, const int* in_sizes, int n_in,
                              void* d_out, int out_size, void* d_ws, size_t ws_size,
                              hipStream_t stream)
{
    const float* x     = (const float*)d_in[0];
    const int*   ei    = (const int*)  d_in[1];
    const float* ea    = (const float*)d_in[2];
    const float* c1_w1 = (const float*)d_in[3];
    const float* c1_b1 = (const float*)d_in[4];
    const float* c1_w2 = (const float*)d_in[5];
    const float* c1_b2 = (const float*)d_in[6];
    const float* c2_w1 = (const float*)d_in[7];
    const float* c2_b1 = (const float*)d_in[8];
    const float* c2_w2 = (const float*)d_in[9];
    const float* c2_b2 = (const float*)d_in[10];
    const float* l1_w  = (const float*)d_in[11];
    const float* l1_b  = (const float*)d_in[12];
    const float* l2_w  = (const float*)d_in[13];
    const float* l2_b  = (const float*)d_in[14];
    float* out = (float*)d_out;

    const int N = in_sizes[0] / 4;   // 100000
    const int E = in_sizes[2] / 8;   // 1600000
    const int nch = (N + CHUNK - 1) / CHUNK;

    const int BLK = 256;
    const int egrid = (E + BLK - 1) / BLK;
    const int ggrid = (N + 31) / 32;

    size_t szN16f = (size_t)N * 16 * 4;
    size_t szN16h = (size_t)N * 16 * 2;
    size_t szN    = ((size_t)N * 4 + 15) & ~(size_t)15;
    size_t szEh   = ((size_t)E * 2 + 15) & ~(size_t)15;
    size_t szE4   = (size_t)E * 4;
    size_t szE16  = (size_t)E * 16;
    size_t szE32  = (size_t)E * 32;

    // ---- Tier A layout (~100 MB): MFMA path ----
    size_t pos_off  = 0;
    size_t srcp_off = pos_off  + szN;
    size_t dstp_off = srcp_off + szE4;
    size_t eap_off  = dstp_off + szE4;
    size_t hws_off  = eap_off  + szE16;
    size_t hwdh_off = hws_off  + szN16f;
    size_t m2h_off  = hwdh_off + szN16h;
    size_t needA    = m2h_off  + szE32 + 256;

    if (ws_size >= needA) {
        int*            pos  = (int*)  ((char*)d_ws + pos_off);
        int*            srcp = (int*)  ((char*)d_ws + srcp_off);
        int*            dstp = (int*)  ((char*)d_ws + dstp_off);
        _Float16*       eap  = (_Float16*)((char*)d_ws + eap_off);
        float*          hw_s = (float*)((char*)d_ws + hws_off);
        unsigned short* hwdh = (unsigned short*)((char*)d_ws + hwdh_off);
        _Float16*       m2h  = (_Float16*)((char*)d_ws + m2h_off);
        // overlays inside m2h region (dead before edge_mlp1 writes it)
        int*            deg  = (int*)  ((char*)d_ws + m2h_off);
        unsigned short* r    = (unsigned short*)((char*)d_ws + m2h_off + szN);
        int*            csum = (int*)  ((char*)d_ws + m2h_off + szN + szEh);
        int*            coff = (int*)  ((char*)d_ws + m2h_off + szN + szEh + 4096);

        hipMemsetAsync(deg, 0, (size_t)N * 4, stream);
        rank_kernel<<<egrid, BLK, 0, stream>>>(ei, deg, r, E);
        scan_chunk_sums<<<nch, BLK, 0, stream>>>(deg, csum, N);
        scan_chunk_off<<<1, 64, 0, stream>>>(csum, coff, nch);
        scan_within_excl<<<nch, BLK, 0, stream>>>(deg, pos, coff, N);
        scatter_perm<<<egrid, BLK, 0, stream>>>(ei, ea, pos, r, srcp, dstp,
                                                (uint4*)eap, E);
        edge_mlp1<<<2048, BLK, 0, stream>>>(x, srcp, dstp, eap,
                                            c1_w1, c1_b1, c1_w2, c1_b2, m2h, E);
        segmax1_hw<<<ggrid, BLK, 0, stream>>>(m2h, pos, c2_w1, c2_b1,
                                              hw_s, hwdh, N, E);
        edge_mlp2<<<2048, BLK, 0, stream>>>(hw_s, hwdh, srcp, dstp, eap,
                                            c2_w1, c2_w2, c2_b2, m2h, E);
        segmax2_head<<<ggrid, BLK, 0, stream>>>(m2h, pos, l1_w, l1_b, l2_w, l2_b,
                                                out, N, E);
        return;
    }

    // ---- Tier B: round-4 layout (~53 MB) ----
    size_t b_hws  = 0;
    size_t b_hwdh = b_hws  + szN16f;
    size_t b_deg  = b_hwdh + szN16h;
    size_t b_pos  = b_deg  + szN;
    size_t b_r    = b_pos  + szN;
    size_t b_src  = b_r    + szEh;
    size_t b_dst  = b_src  + szE4;
    size_t b_eap  = b_dst  + szE4;
    size_t b_cs   = b_eap  + szE16;
    size_t b_cf   = b_cs   + 4096;

    float*          hw_s = (float*)((char*)d_ws + b_hws);
    unsigned short* hwdh = (unsigned short*)((char*)d_ws + b_hwdh);
    int*            deg  = (int*)  ((char*)d_ws + b_deg);
    int*            pos  = (int*)  ((char*)d_ws + b_pos);
    unsigned short* r    = (unsigned short*)((char*)d_ws + b_r);
    int*            srcp = (int*)  ((char*)d_ws + b_src);
    int*            dstp = (int*)  ((char*)d_ws + b_dst);
    uint4*          eap  = (uint4*)((char*)d_ws + b_eap);
    int*            csum = (int*)  ((char*)d_ws + b_cs);
    int*            coff = (int*)  ((char*)d_ws + b_cf);

    hipMemsetAsync(deg, 0, (size_t)N * 4, stream);
    rank_kernel<<<egrid, BLK, 0, stream>>>(ei, deg, r, E);
    scan_chunk_sums<<<nch, BLK, 0, stream>>>(deg, csum, N);
    scan_chunk_off<<<1, 64, 0, stream>>>(csum, coff, nch);
    scan_within_excl<<<nch, BLK, 0, stream>>>(deg, pos, coff, N);
    scatter_perm<<<egrid, BLK, 0, stream>>>(ei, ea, pos, r, srcp, dstp, eap, E);
    conv1_g8<<<ggrid, BLK, 0, stream>>>(x, dstp, eap, c1_w1, c1_b1, c1_w2, c1_b2,
                                        c2_w1, c2_b1, pos, hw_s, hwdh, N, E);
    conv2_g8_head<<<ggrid, BLK, 0, stream>>>(hw_s, hwdh, dstp, eap,
                                             c2_w1, c2_w2, c2_b2,
                                             l1_w, l1_b, l2_w, l2_b,
                                             pos, out, N, E);
}

// Round 6
// 393.221 us; speedup vs baseline: 5.4616x; 1.0020x over previous
//
#include <hip/hip_runtime.h>
#include <hip/hip_fp16.h>

#define CHUNK 1024

typedef _Float16 half8 __attribute__((ext_vector_type(8)));
typedef float floatx4 __attribute__((ext_vector_type(4)));

__device__ __forceinline__ unsigned int pack2(float a, float b) {
    __half2 h = __floats2half2_rn(a, b);
    return *(unsigned int*)&h;
}
__device__ __forceinline__ float2 unpack2(unsigned int u) {
    __half2 h = *(__half2*)&u;
    return __half22float2(h);
}

// ===========================================================================
// CSR position build (no payload permutation):
//   r[e] = rank of edge e within its src bucket (atomicAdd histogram)
//   pos  = exclusive scan of deg
// Edge e's CSR slot: p = pos[ei[e]] + r[e]. Order within a segment is
// nondeterministic (atomic order) — segment_max is order-independent.
// ===========================================================================
__global__ __launch_bounds__(256) void rank_kernel(
    const int* __restrict__ ei, int* __restrict__ deg,
    unsigned short* __restrict__ r, int E)
{
    int e = blockIdx.x * 256 + threadIdx.x;
    if (e < E) r[e] = (unsigned short)atomicAdd(&deg[ei[e]], 1);
}

__global__ __launch_bounds__(256) void scan_chunk_sums(
    const int* __restrict__ v, int* __restrict__ csum, int N)
{
    __shared__ int s[256];
    int base = blockIdx.x * CHUNK;
    int t = threadIdx.x;
    int acc = 0;
    #pragma unroll
    for (int i = 0; i < CHUNK / 256; ++i) {
        int idx = base + t + i * 256;
        if (idx < N) acc += v[idx];
    }
    s[t] = acc; __syncthreads();
    for (int o = 128; o > 0; o >>= 1) {
        if (t < o) s[t] += s[t + o];
        __syncthreads();
    }
    if (t == 0) csum[blockIdx.x] = s[0];
}

__global__ void scan_chunk_off(
    const int* __restrict__ csum, int* __restrict__ coff, int nch)
{
    if (threadIdx.x == 0 && blockIdx.x == 0) {
        int acc = 0;
        for (int i = 0; i < nch; ++i) { coff[i] = acc; acc += csum[i]; }
    }
}

__global__ __launch_bounds__(256) void scan_within_excl(
    const int* __restrict__ deg, int* __restrict__ pos,
    const int* __restrict__ coff, int N)
{
    __shared__ int s[256];
    int t = threadIdx.x;
    int base = blockIdx.x * CHUNK + t * 4;
    int v0 = 0, v1 = 0, v2 = 0, v3 = 0;
    if (base + 0 < N) v0 = deg[base + 0];
    if (base + 1 < N) v1 = deg[base + 1];
    if (base + 2 < N) v2 = deg[base + 2];
    if (base + 3 < N) v3 = deg[base + 3];
    s[t] = v0 + v1 + v2 + v3;
    __syncthreads();
    for (int o = 1; o < 256; o <<= 1) {
        int add = (t >= o) ? s[t - o] : 0;
        __syncthreads();
        s[t] += add;
        __syncthreads();
    }
    int run = coff[blockIdx.x] + (t > 0 ? s[t - 1] : 0);
    if (base + 0 < N) pos[base + 0] = run; run += v0;
    if (base + 1 < N) pos[base + 1] = run; run += v1;
    if (base + 2 < N) pos[base + 2] = run; run += v2;
    if (base + 3 < N) pos[base + 3] = run;
}

// ===========================================================================
// MFMA edge-MLP kernels, ORIGINAL edge order (coalesced ei/ea reads), output
// scattered to CSR slot p (32 B aligned records -> clean sector writes).
//   16x16x32 layouts: A[m=lane&15][k=8q+j], B[k=8q+j][n=lane&15],
//   C/D: col=lane&15, row=4q+reg.
// ===========================================================================
__global__ __launch_bounds__(256) void edge_mlp1(
    const float* __restrict__ x,          // [N,4]
    const int*   __restrict__ ei,         // [2,E]
    const float* __restrict__ ea,         // [E,8]
    const int*   __restrict__ pos,        // [N] start offsets
    const unsigned short* __restrict__ r, // [E] ranks
    const float* __restrict__ w1, const float* __restrict__ b1,  // 16x16
    const float* __restrict__ w2, const float* __restrict__ b2,  // 16x16
    _Float16* __restrict__ m2h,           // [E,16] CSR-ordered output
    int E)
{
    __shared__ float    lsf[4][16][20];
    __shared__ _Float16 lsh[4][16][20];
    int lane = threadIdx.x & 63;
    int w    = threadIdx.x >> 6;
    int e16  = lane & 15, q = lane >> 4;
    int wgid = blockIdx.x * 4 + w;
    int nw   = gridDim.x * 4;
    int ntiles = (E + 15) >> 4;

    half8 B1, B2;
    #pragma unroll
    for (int j = 0; j < 8; ++j) { B1[j] = (_Float16)0.f; B2[j] = (_Float16)0.f; }
    if (q < 2) {
        #pragma unroll
        for (int j = 0; j < 8; ++j) {
            B1[j] = (_Float16)w1[(8 * q + j) * 16 + e16];
            B2[j] = (_Float16)w2[(8 * q + j) * 16 + e16];
        }
    }
    float b1c = b1[e16], b2c = b2[e16];

    for (int tile = wgid; tile < ntiles; tile += nw) {
        int ebase = tile << 4;
        int e = ebase + e16;          // this lane's A/output row

        half8 A;
        #pragma unroll
        for (int j = 0; j < 8; ++j) A[j] = (_Float16)0.f;
        if (q == 0 && e < E) {
            int s = ei[e], d = ei[E + e];
            float4 xs = *(const float4*)(x + (size_t)s * 4);
            float4 xd = *(const float4*)(x + (size_t)d * 4);
            A[0] = (_Float16)xs.x; A[1] = (_Float16)xs.y;
            A[2] = (_Float16)xs.z; A[3] = (_Float16)xs.w;
            A[4] = (_Float16)xd.x; A[5] = (_Float16)xd.y;
            A[6] = (_Float16)xd.z; A[7] = (_Float16)xd.w;
        } else if (q == 1 && e < E) {
            float4 a0 = *(const float4*)(ea + (size_t)e * 8);
            float4 a1 = *(const float4*)(ea + (size_t)e * 8 + 4);
            A[0] = (_Float16)a0.x; A[1] = (_Float16)a0.y;
            A[2] = (_Float16)a0.z; A[3] = (_Float16)a0.w;
            A[4] = (_Float16)a1.x; A[5] = (_Float16)a1.y;
            A[6] = (_Float16)a1.z; A[7] = (_Float16)a1.w;
        }

        floatx4 C = {b1c, b1c, b1c, b1c};
        C = __builtin_amdgcn_mfma_f32_16x16x32_f16(A, B1, C, 0, 0, 0);
        #pragma unroll
        for (int i = 0; i < 4; ++i)
            lsf[w][4 * q + i][e16] = fmaxf(C[i], 0.0f);
        __builtin_amdgcn_wave_barrier();

        half8 A2;
        #pragma unroll
        for (int j = 0; j < 8; ++j) A2[j] = (_Float16)0.f;
        if (q < 2) {
            #pragma unroll
            for (int j = 0; j < 8; ++j)
                A2[j] = (_Float16)lsf[w][e16][8 * q + j];
        }
        floatx4 C2 = {b2c, b2c, b2c, b2c};
        C2 = __builtin_amdgcn_mfma_f32_16x16x32_f16(A2, B2, C2, 0, 0, 0);
        __builtin_amdgcn_wave_barrier();
        #pragma unroll
        for (int i = 0; i < 4; ++i)
            lsh[w][4 * q + i][e16] = (_Float16)C2[i];
        __builtin_amdgcn_wave_barrier();

        if (e < E) {
            int s2 = ei[e];
            int p = pos[s2] + (int)r[e];
            uint2 v = *(uint2*)&lsh[w][e16][4 * q];
            *(uint2*)(m2h + (size_t)p * 16 + 4 * q) = v;
        }
    }
}

__global__ __launch_bounds__(256) void edge_mlp2(
    const float* __restrict__ hw_s,            // [N,16] fp32 (cb1 folded)
    const unsigned short* __restrict__ hw_dh,  // [N,16] fp16
    const int*   __restrict__ ei,
    const float* __restrict__ ea,
    const int*   __restrict__ pos,
    const unsigned short* __restrict__ r,
    const float* __restrict__ w1,              // [40,16] rows 32:40 used
    const float* __restrict__ w2, const float* __restrict__ b2,
    _Float16* __restrict__ m2h, int E)
{
    __shared__ float    lsf[4][16][20];
    __shared__ _Float16 lsh[4][16][20];
    int lane = threadIdx.x & 63;
    int w    = threadIdx.x >> 6;
    int e16  = lane & 15, q = lane >> 4;
    int wgid = blockIdx.x * 4 + w;
    int nw   = gridDim.x * 4;
    int ntiles = (E + 15) >> 4;
    const __half* hwd = (const __half*)hw_dh;

    half8 B1, B2;
    #pragma unroll
    for (int j = 0; j < 8; ++j) { B1[j] = (_Float16)0.f; B2[j] = (_Float16)0.f; }
    if (q == 0) {
        #pragma unroll
        for (int j = 0; j < 8; ++j)
            B1[j] = (_Float16)w1[(32 + j) * 16 + e16];
    }
    if (q < 2) {
        #pragma unroll
        for (int j = 0; j < 8; ++j)
            B2[j] = (_Float16)w2[(8 * q + j) * 16 + e16];
    }
    float b2c = b2[e16];

    for (int tile = wgid; tile < ntiles; tile += nw) {
        int ebase = tile << 4;
        int e = ebase + e16;

        half8 A;
        #pragma unroll
        for (int j = 0; j < 8; ++j) A[j] = (_Float16)0.f;
        if (q == 0 && e < E) {
            float4 a0 = *(const float4*)(ea + (size_t)e * 8);
            float4 a1 = *(const float4*)(ea + (size_t)e * 8 + 4);
            A[0] = (_Float16)a0.x; A[1] = (_Float16)a0.y;
            A[2] = (_Float16)a0.z; A[3] = (_Float16)a0.w;
            A[4] = (_Float16)a1.x; A[5] = (_Float16)a1.y;
            A[6] = (_Float16)a1.z; A[7] = (_Float16)a1.w;
        }

        // C init: hw_s[src[row]][col] + hw_d[dst[row]][col], row=4q+i, col=e16
        floatx4 C;
        #pragma unroll
        for (int i = 0; i < 4; ++i) {
            int rr = ebase + 4 * q + i;
            float v = 0.0f;
            if (rr < E) {
                int s = ei[rr], d = ei[E + rr];
                v = hw_s[(size_t)s * 16 + e16]
                  + __half2float(hwd[(size_t)d * 16 + e16]);
            }
            C[i] = v;
        }
        C = __builtin_amdgcn_mfma_f32_16x16x32_f16(A, B1, C, 0, 0, 0);
        #pragma unroll
        for (int i = 0; i < 4; ++i)
            lsf[w][4 * q + i][e16] = fmaxf(C[i], 0.0f);
        __builtin_amdgcn_wave_barrier();

        half8 A2;
        #pragma unroll
        for (int j = 0; j < 8; ++j) A2[j] = (_Float16)0.f;
        if (q < 2) {
            #pragma unroll
            for (int j = 0; j < 8; ++j)
                A2[j] = (_Float16)lsf[w][e16][8 * q + j];
        }
        floatx4 C2 = {b2c, b2c, b2c, b2c};
        C2 = __builtin_amdgcn_mfma_f32_16x16x32_f16(A2, B2, C2, 0, 0, 0);
        __builtin_amdgcn_wave_barrier();
        #pragma unroll
        for (int i = 0; i < 4; ++i)
            lsh[w][4 * q + i][e16] = (_Float16)C2[i];
        __builtin_amdgcn_wave_barrier();

        if (e < E) {
            int s2 = ei[e];
            int p = pos[s2] + (int)r[e];
            uint2 v = *(uint2*)&lsh[w][e16][4 * q];
            *(uint2*)(m2h + (size_t)p * 16 + 4 * q) = v;
        }
    }
}

// ===========================================================================
// Streaming segment-max kernels (8 lanes/node) + fused epilogues.
// ===========================================================================
__global__ __launch_bounds__(256) void segmax1_hw(
    const _Float16* __restrict__ m2h, const int* __restrict__ pos,
    const float* __restrict__ cw1, const float* __restrict__ cb1, // conv2 w1/b1
    float* __restrict__ hw_s, unsigned short* __restrict__ hw_dh,
    int N, int E)
{
    int tid = threadIdx.x;
    int n = blockIdx.x * 32 + (tid >> 3);
    if (n >= N) return;
    int g = tid & 7;
    int start = pos[n];
    int end = (n + 1 < N) ? pos[n + 1] : E;

    float acc[16];
    #pragma unroll
    for (int j = 0; j < 16; ++j) acc[j] = 0.0f;

    for (int k = start + g; k < end; k += 8) {
        uint4 u0 = *(const uint4*)(m2h + (size_t)k * 16);
        uint4 u1 = *(const uint4*)(m2h + (size_t)k * 16 + 8);
        float2 f;
        f = unpack2(u0.x); acc[0]  = fmaxf(acc[0],  f.x); acc[1]  = fmaxf(acc[1],  f.y);
        f = unpack2(u0.y); acc[2]  = fmaxf(acc[2],  f.x); acc[3]  = fmaxf(acc[3],  f.y);
        f = unpack2(u0.z); acc[4]  = fmaxf(acc[4],  f.x); acc[5]  = fmaxf(acc[5],  f.y);
        f = unpack2(u0.w); acc[6]  = fmaxf(acc[6],  f.x); acc[7]  = fmaxf(acc[7],  f.y);
        f = unpack2(u1.x); acc[8]  = fmaxf(acc[8],  f.x); acc[9]  = fmaxf(acc[9],  f.y);
        f = unpack2(u1.y); acc[10] = fmaxf(acc[10], f.x); acc[11] = fmaxf(acc[11], f.y);
        f = unpack2(u1.z); acc[12] = fmaxf(acc[12], f.x); acc[13] = fmaxf(acc[13], f.y);
        f = unpack2(u1.w); acc[14] = fmaxf(acc[14], f.x); acc[15] = fmaxf(acc[15], f.y);
    }
    #pragma unroll
    for (int mask = 1; mask < 8; mask <<= 1) {
        #pragma unroll
        for (int j = 0; j < 16; ++j)
            acc[j] = fmaxf(acc[j], __shfl_xor(acc[j], mask, 64));
    }

    int j0 = 2 * g, j1 = 2 * g + 1;
    float hs0 = cb1[j0], hs1 = cb1[j1], hd0 = 0.0f, hd1 = 0.0f;
    #pragma unroll
    for (int k = 0; k < 16; ++k) {
        float ak = acc[k];
        hs0 = fmaf(ak, cw1[k * 16 + j0], hs0);
        hs1 = fmaf(ak, cw1[k * 16 + j1], hs1);
        hd0 = fmaf(ak, cw1[(16 + k) * 16 + j0], hd0);
        hd1 = fmaf(ak, cw1[(16 + k) * 16 + j1], hd1);
    }
    *(float2*)(hw_s + (size_t)n * 16 + j0) = make_float2(hs0, hs1);
    ((unsigned int*)hw_dh)[(size_t)n * 8 + g] = pack2(hd0, hd1);
}

__global__ __launch_bounds__(256) void segmax2_head(
    const _Float16* __restrict__ m2h, const int* __restrict__ pos,
    const float* __restrict__ l1w, const float* __restrict__ l1b,
    const float* __restrict__ l2w, const float* __restrict__ l2b,
    float* __restrict__ out, int N, int E)
{
    int tid = threadIdx.x;
    int n = blockIdx.x * 32 + (tid >> 3);
    if (n >= N) return;
    int g = tid & 7;
    int start = pos[n];
    int end = (n + 1 < N) ? pos[n + 1] : E;

    float acc[16];
    #pragma unroll
    for (int j = 0; j < 16; ++j) acc[j] = 0.0f;

    for (int k = start + g; k < end; k += 8) {
        uint4 u0 = *(const uint4*)(m2h + (size_t)k * 16);
        uint4 u1 = *(const uint4*)(m2h + (size_t)k * 16 + 8);
        float2 f;
        f = unpack2(u0.x); acc[0]  = fmaxf(acc[0],  f.x); acc[1]  = fmaxf(acc[1],  f.y);
        f = unpack2(u0.y); acc[2]  = fmaxf(acc[2],  f.x); acc[3]  = fmaxf(acc[3],  f.y);
        f = unpack2(u0.z); acc[4]  = fmaxf(acc[4],  f.x); acc[5]  = fmaxf(acc[5],  f.y);
        f = unpack2(u0.w); acc[6]  = fmaxf(acc[6],  f.x); acc[7]  = fmaxf(acc[7],  f.y);
        f = unpack2(u1.x); acc[8]  = fmaxf(acc[8],  f.x); acc[9]  = fmaxf(acc[9],  f.y);
        f = unpack2(u1.y); acc[10] = fmaxf(acc[10], f.x); acc[11] = fmaxf(acc[11], f.y);
        f = unpack2(u1.z); acc[12] = fmaxf(acc[12], f.x); acc[13] = fmaxf(acc[13], f.y);
        f = unpack2(u1.w); acc[14] = fmaxf(acc[14], f.x); acc[15] = fmaxf(acc[15], f.y);
    }
    #pragma unroll
    for (int mask = 1; mask < 8; mask <<= 1) {
        #pragma unroll
        for (int j = 0; j < 16; ++j)
            acc[j] = fmaxf(acc[j], __shfl_xor(acc[j], mask, 64));
    }

    float t2[16];
    #pragma unroll
    for (int j = 0; j < 16; ++j) t2[j] = l1b[j];
    #pragma unroll
    for (int kk = 0; kk < 16; ++kk) {
        float ak = acc[kk];
        #pragma unroll
        for (int j = 0; j < 16; ++j) t2[j] = fmaf(ak, l1w[kk * 16 + j], t2[j]);
    }
    float r2 = l2b[0];
    #pragma unroll
    for (int j = 0; j < 16; ++j) r2 = fmaf(fmaxf(t2[j], 0.0f), l2w[j], r2);
    if (g == 0) out[n] = r2;
}

// ===========================================================================
extern "C" void kernel_launch(void* const* d_in, const int* in_sizes, int n_in,
                              void* d_out, int out_size, void* d_ws, size_t ws_size,
                              hipStream_t stream)
{
    const float* x     = (const float*)d_in[0];
    const int*   ei    = (const int*)  d_in[1];
    const float* ea    = (const float*)d_in[2];
    const float* c1_w1 = (const float*)d_in[3];
    const float* c1_b1 = (const float*)d_in[4];
    const float* c1_w2 = (const float*)d_in[5];
    const float* c1_b2 = (const float*)d_in[6];
    const float* c2_w1 = (const float*)d_in[7];
    const float* c2_b1 = (const float*)d_in[8];
    const float* c2_w2 = (const float*)d_in[9];
    const float* c2_b2 = (const float*)d_in[10];
    const float* l1_w  = (const float*)d_in[11];
    const float* l1_b  = (const float*)d_in[12];
    const float* l2_w  = (const float*)d_in[13];
    const float* l2_b  = (const float*)d_in[14];
    float* out = (float*)d_out;

    const int N = in_sizes[0] / 4;   // 100000
    const int E = in_sizes[2] / 8;   // 1600000
    const int nch = (N + CHUNK - 1) / CHUNK;

    const int BLK = 256;
    const int egrid = (E + BLK - 1) / BLK;
    const int ggrid = (N + 31) / 32;

    size_t szN16f = (size_t)N * 16 * 4;                 // 6.4 MB
    size_t szN16h = (size_t)N * 16 * 2;                 // 3.2 MB
    size_t szN    = ((size_t)N * 4 + 15) & ~(size_t)15;
    size_t szEh   = ((size_t)E * 2 + 15) & ~(size_t)15; // 3.2 MB
    size_t szE32  = (size_t)E * 32;                     // 51.2 MB

    // ---- workspace (~64.5 MB; rounds 4/5 proved ws >= ~100 MB) ----
    size_t pos_off  = 0;
    size_t r_off    = pos_off  + szN;
    size_t hws_off  = r_off    + szEh;
    size_t hwdh_off = hws_off  + szN16f;
    size_t m2h_off  = hwdh_off + szN16h;
    // overlays inside m2h (dead before edge_mlp1 writes it):
    size_t deg_off  = m2h_off;
    size_t cs_off   = deg_off  + szN;
    size_t cf_off   = cs_off   + 4096;

    int*            pos  = (int*)  ((char*)d_ws + pos_off);
    unsigned short* r    = (unsigned short*)((char*)d_ws + r_off);
    float*          hw_s = (float*)((char*)d_ws + hws_off);
    unsigned short* hwdh = (unsigned short*)((char*)d_ws + hwdh_off);
    _Float16*       m2h  = (_Float16*)((char*)d_ws + m2h_off);
    int*            deg  = (int*)  ((char*)d_ws + deg_off);
    int*            csum = (int*)  ((char*)d_ws + cs_off);
    int*            coff = (int*)  ((char*)d_ws + cf_off);

    hipMemsetAsync(deg, 0, (size_t)N * 4, stream);
    rank_kernel<<<egrid, BLK, 0, stream>>>(ei, deg, r, E);
    scan_chunk_sums<<<nch, BLK, 0, stream>>>(deg, csum, N);
    scan_chunk_off<<<1, 64, 0, stream>>>(csum, coff, nch);
    scan_within_excl<<<nch, BLK, 0, stream>>>(deg, pos, coff, N);
    edge_mlp1<<<2048, BLK, 0, stream>>>(x, ei, ea, pos, r,
                                        c1_w1, c1_b1, c1_w2, c1_b2, m2h, E);
    segmax1_hw<<<ggrid, BLK, 0, stream>>>(m2h, pos, c2_w1, c2_b1,
                                          hw_s, hwdh, N, E);
    edge_mlp2<<<2048, BLK, 0, stream>>>(hw_s, hwdh, ei, ea, pos, r,
                                        c2_w1, c2_w2, c2_b2, m2h, E);
    segmax2_head<<<ggrid, BLK, 0, stream>>>(m2h, pos, l1_w, l1_b, l2_w, l2_b,
                                            out, N, E);
}

// Round 7
// 374.987 us; speedup vs baseline: 5.7272x; 1.0486x over previous
//
#include <hip/hip_runtime.h>
#include <hip/hip_fp16.h>

#define CHUNK 1024

typedef _Float16 half8 __attribute__((ext_vector_type(8)));
typedef float floatx4 __attribute__((ext_vector_type(4)));

__device__ __forceinline__ unsigned int pack2(float a, float b) {
    __half2 h = __floats2half2_rn(a, b);
    return *(unsigned int*)&h;
}
__device__ __forceinline__ float2 unpack2(unsigned int u) {
    __half2 h = *(__half2*)&u;
    return __half22float2(h);
}

// ===========================================================================
// rank + fp16-convert fused: r[e] = rank within src bucket (atomic histo),
// eah[e] = fp16(ea[e]). The atomics are latency-bound; the streaming cvt
// rides along on idle BW.
// ===========================================================================
__global__ __launch_bounds__(256) void rank_cvt(
    const int* __restrict__ ei, const float* __restrict__ ea,
    int* __restrict__ deg, unsigned short* __restrict__ r,
    _Float16* __restrict__ eah, int E)
{
    int e = blockIdx.x * 256 + threadIdx.x;
    if (e >= E) return;
    r[e] = (unsigned short)atomicAdd(&deg[ei[e]], 1);
    float4 a0 = *(const float4*)(ea + (size_t)e * 8);
    float4 a1 = *(const float4*)(ea + (size_t)e * 8 + 4);
    half8 h;
    h[0] = (_Float16)a0.x; h[1] = (_Float16)a0.y;
    h[2] = (_Float16)a0.z; h[3] = (_Float16)a0.w;
    h[4] = (_Float16)a1.x; h[5] = (_Float16)a1.y;
    h[6] = (_Float16)a1.z; h[7] = (_Float16)a1.w;
    *(half8*)(eah + (size_t)e * 8) = h;
}

__global__ __launch_bounds__(256) void scan_chunk_sums(
    const int* __restrict__ v, int* __restrict__ csum, int N)
{
    __shared__ int s[256];
    int base = blockIdx.x * CHUNK;
    int t = threadIdx.x;
    int acc = 0;
    #pragma unroll
    for (int i = 0; i < CHUNK / 256; ++i) {
        int idx = base + t + i * 256;
        if (idx < N) acc += v[idx];
    }
    s[t] = acc; __syncthreads();
    for (int o = 128; o > 0; o >>= 1) {
        if (t < o) s[t] += s[t + o];
        __syncthreads();
    }
    if (t == 0) csum[blockIdx.x] = s[0];
}

__global__ void scan_chunk_off(
    const int* __restrict__ csum, int* __restrict__ coff, int nch)
{
    if (threadIdx.x == 0 && blockIdx.x == 0) {
        int acc = 0;
        for (int i = 0; i < nch; ++i) { coff[i] = acc; acc += csum[i]; }
    }
}

__global__ __launch_bounds__(256) void scan_within_excl(
    const int* __restrict__ deg, int* __restrict__ pos,
    const int* __restrict__ coff, int N)
{
    __shared__ int s[256];
    int t = threadIdx.x;
    int base = blockIdx.x * CHUNK + t * 4;
    int v0 = 0, v1 = 0, v2 = 0, v3 = 0;
    if (base + 0 < N) v0 = deg[base + 0];
    if (base + 1 < N) v1 = deg[base + 1];
    if (base + 2 < N) v2 = deg[base + 2];
    if (base + 3 < N) v3 = deg[base + 3];
    s[t] = v0 + v1 + v2 + v3;
    __syncthreads();
    for (int o = 1; o < 256; o <<= 1) {
        int add = (t >= o) ? s[t - o] : 0;
        __syncthreads();
        s[t] += add;
        __syncthreads();
    }
    int run = coff[blockIdx.x] + (t > 0 ? s[t - 1] : 0);
    if (base + 0 < N) pos[base + 0] = run; run += v0;
    if (base + 1 < N) pos[base + 1] = run; run += v1;
    if (base + 2 < N) pos[base + 2] = run; run += v2;
    if (base + 3 < N) pos[base + 3] = run;
}

// ===========================================================================
// MFMA edge-MLP, 64 edges per wave-iteration (4 independent 16x16 tiles).
// Original edge order (coalesced reads); output scattered to CSR slot p
// (32 B full-row writes per lane).
//   16x16x32 layouts: A[m=lane&15][k=8q+j], B[k=8q+j][n=lane&15],
//   C/D: col=lane&15, row=4q+reg.
// ===========================================================================
__global__ __launch_bounds__(256) void edge_mlp1(
    const float* __restrict__ x,          // [N,4]
    const int*   __restrict__ ei,         // [2,E]
    const _Float16* __restrict__ eah,     // [E,8] fp16
    const int*   __restrict__ pos,
    const unsigned short* __restrict__ r,
    const float* __restrict__ w1, const float* __restrict__ b1,  // 16x16
    const float* __restrict__ w2, const float* __restrict__ b2,  // 16x16
    _Float16* __restrict__ m2h,           // [E,16] CSR-ordered
    int E)
{
    __shared__ _Float16 itm[4][4][16][24];   // [wave][tile][row][ch+pad]
    __shared__ int      sd[4][2][64];        // [wave][src/dst][lane]
    int tid = threadIdx.x;
    int w = tid >> 6, lane = tid & 63;
    int e16 = lane & 15, q = lane >> 4;

    half8 B1, B2;
    #pragma unroll
    for (int j = 0; j < 8; ++j) { B1[j] = (_Float16)0.f; B2[j] = (_Float16)0.f; }
    if (q < 2) {
        #pragma unroll
        for (int j = 0; j < 8; ++j) {
            B1[j] = (_Float16)w1[(8 * q + j) * 16 + e16];
            B2[j] = (_Float16)w2[(8 * q + j) * 16 + e16];
        }
    }
    float b1c = b1[e16], b2c = b2[e16];

    int wid = blockIdx.x * 4 + w;
    int nw  = gridDim.x * 4;
    int ntiles = (E + 63) >> 6;

    for (int tile = wid; tile < ntiles; tile += nw) {
        int ebase = tile << 6;
        int e = ebase + lane;
        int s_l = 0, d_l = 0, p_l = 0;
        if (e < E) {
            s_l = ei[e];
            d_l = ei[E + e];
            p_l = pos[s_l] + (int)r[e];
        }
        sd[w][0][lane] = s_l;
        sd[w][1][lane] = d_l;
        __builtin_amdgcn_wave_barrier();

        // phase A: build 4 independent A-fragments (batched loads)
        half8 A[4];
        #pragma unroll
        for (int t = 0; t < 4; ++t) {
            half8 a;
            #pragma unroll
            for (int j = 0; j < 8; ++j) a[j] = (_Float16)0.f;
            int et = ebase + 16 * t + e16;
            if (q == 0 && et < E) {
                int s = sd[w][0][16 * t + e16];
                int d = sd[w][1][16 * t + e16];
                float4 xs = *(const float4*)(x + (size_t)s * 4);
                float4 xd = *(const float4*)(x + (size_t)d * 4);
                a[0] = (_Float16)xs.x; a[1] = (_Float16)xs.y;
                a[2] = (_Float16)xs.z; a[3] = (_Float16)xs.w;
                a[4] = (_Float16)xd.x; a[5] = (_Float16)xd.y;
                a[6] = (_Float16)xd.z; a[7] = (_Float16)xd.w;
            } else if (q == 1 && et < E) {
                a = *(const half8*)(eah + (size_t)et * 8);
            }
            A[t] = a;
        }

        // layer 1: 4 independent MFMAs
        floatx4 C[4];
        #pragma unroll
        for (int t = 0; t < 4; ++t) {
            floatx4 c = {b1c, b1c, b1c, b1c};
            C[t] = __builtin_amdgcn_mfma_f32_16x16x32_f16(A[t], B1, c, 0, 0, 0);
        }
        #pragma unroll
        for (int t = 0; t < 4; ++t)
            #pragma unroll
            for (int i = 0; i < 4; ++i)
                itm[w][t][4 * q + i][e16] = (_Float16)fmaxf(C[t][i], 0.0f);
        __builtin_amdgcn_wave_barrier();

        // layer 2
        half8 A2[4];
        #pragma unroll
        for (int t = 0; t < 4; ++t) {
            half8 a;
            #pragma unroll
            for (int j = 0; j < 8; ++j) a[j] = (_Float16)0.f;
            if (q < 2) a = *(const half8*)&itm[w][t][e16][8 * q];
            A2[t] = a;
        }
        __builtin_amdgcn_wave_barrier();
        floatx4 C2[4];
        #pragma unroll
        for (int t = 0; t < 4; ++t) {
            floatx4 c = {b2c, b2c, b2c, b2c};
            C2[t] = __builtin_amdgcn_mfma_f32_16x16x32_f16(A2[t], B2, c, 0, 0, 0);
        }
        #pragma unroll
        for (int t = 0; t < 4; ++t)
            #pragma unroll
            for (int i = 0; i < 4; ++i)
                itm[w][t][4 * q + i][e16] = (_Float16)C2[t][i];
        __builtin_amdgcn_wave_barrier();

        // each lane writes its own edge's full 32 B row to CSR slot
        if (e < E) {
            half8 lo = *(const half8*)&itm[w][q][e16][0];
            half8 hi = *(const half8*)&itm[w][q][e16][8];
            *(half8*)(m2h + (size_t)p_l * 16)     = lo;
            *(half8*)(m2h + (size_t)p_l * 16 + 8) = hi;
        }
        __builtin_amdgcn_wave_barrier();   // protect itm for next iteration
    }
}

__global__ __launch_bounds__(256) void edge_mlp2(
    const float* __restrict__ hw_s,            // [N,16] fp32 (cb1 folded)
    const unsigned short* __restrict__ hw_dh,  // [N,16] fp16
    const int*   __restrict__ ei,
    const _Float16* __restrict__ eah,
    const int*   __restrict__ pos,
    const unsigned short* __restrict__ r,
    const float* __restrict__ w1,              // [40,16] rows 32:40 used
    const float* __restrict__ w2, const float* __restrict__ b2,
    _Float16* __restrict__ m2h, int E)
{
    __shared__ _Float16 itm[4][4][16][24];
    __shared__ int      sd[4][2][64];
    int tid = threadIdx.x;
    int w = tid >> 6, lane = tid & 63;
    int e16 = lane & 15, q = lane >> 4;
    const __half* hwd = (const __half*)hw_dh;

    half8 B1, B2;
    #pragma unroll
    for (int j = 0; j < 8; ++j) { B1[j] = (_Float16)0.f; B2[j] = (_Float16)0.f; }
    if (q == 0) {
        #pragma unroll
        for (int j = 0; j < 8; ++j)
            B1[j] = (_Float16)w1[(32 + j) * 16 + e16];
    }
    if (q < 2) {
        #pragma unroll
        for (int j = 0; j < 8; ++j)
            B2[j] = (_Float16)w2[(8 * q + j) * 16 + e16];
    }
    float b2c = b2[e16];

    int wid = blockIdx.x * 4 + w;
    int nw  = gridDim.x * 4;
    int ntiles = (E + 63) >> 6;

    for (int tile = wid; tile < ntiles; tile += nw) {
        int ebase = tile << 6;
        int e = ebase + lane;
        int s_l = 0, d_l = 0, p_l = 0;
        if (e < E) {
            s_l = ei[e];
            d_l = ei[E + e];
            p_l = pos[s_l] + (int)r[e];
        }
        sd[w][0][lane] = s_l;
        sd[w][1][lane] = d_l;
        __builtin_amdgcn_wave_barrier();

        half8 A[4];
        #pragma unroll
        for (int t = 0; t < 4; ++t) {
            half8 a;
            #pragma unroll
            for (int j = 0; j < 8; ++j) a[j] = (_Float16)0.f;
            int et = ebase + 16 * t + e16;
            if (q == 0 && et < E)
                a = *(const half8*)(eah + (size_t)et * 8);
            A[t] = a;
        }

        // C init: hw_s[src[row]][col] + hw_d[dst[row]][col]
        floatx4 C[4];
        #pragma unroll
        for (int t = 0; t < 4; ++t) {
            floatx4 c;
            #pragma unroll
            for (int i = 0; i < 4; ++i) {
                int li = 16 * t + 4 * q + i;
                int rr = ebase + li;
                float v = 0.0f;
                if (rr < E) {
                    int s = sd[w][0][li];
                    int d = sd[w][1][li];
                    v = hw_s[(size_t)s * 16 + e16]
                      + __half2float(hwd[(size_t)d * 16 + e16]);
                }
                c[i] = v;
            }
            C[t] = __builtin_amdgcn_mfma_f32_16x16x32_f16(A[t], B1, c, 0, 0, 0);
        }
        #pragma unroll
        for (int t = 0; t < 4; ++t)
            #pragma unroll
            for (int i = 0; i < 4; ++i)
                itm[w][t][4 * q + i][e16] = (_Float16)fmaxf(C[t][i], 0.0f);
        __builtin_amdgcn_wave_barrier();

        half8 A2[4];
        #pragma unroll
        for (int t = 0; t < 4; ++t) {
            half8 a;
            #pragma unroll
            for (int j = 0; j < 8; ++j) a[j] = (_Float16)0.f;
            if (q < 2) a = *(const half8*)&itm[w][t][e16][8 * q];
            A2[t] = a;
        }
        __builtin_amdgcn_wave_barrier();
        floatx4 C2[4];
        #pragma unroll
        for (int t = 0; t < 4; ++t) {
            floatx4 c = {b2c, b2c, b2c, b2c};
            C2[t] = __builtin_amdgcn_mfma_f32_16x16x32_f16(A2[t], B2, c, 0, 0, 0);
        }
        #pragma unroll
        for (int t = 0; t < 4; ++t)
            #pragma unroll
            for (int i = 0; i < 4; ++i)
                itm[w][t][4 * q + i][e16] = (_Float16)C2[t][i];
        __builtin_amdgcn_wave_barrier();

        if (e < E) {
            half8 lo = *(const half8*)&itm[w][q][e16][0];
            half8 hi = *(const half8*)&itm[w][q][e16][8];
            *(half8*)(m2h + (size_t)p_l * 16)     = lo;
            *(half8*)(m2h + (size_t)p_l * 16 + 8) = hi;
        }
        __builtin_amdgcn_wave_barrier();
    }
}

// ===========================================================================
// Streaming segment-max kernels (8 lanes/node) + fused epilogues.
// ===========================================================================
__global__ __launch_bounds__(256) void segmax1_hw(
    const _Float16* __restrict__ m2h, const int* __restrict__ pos,
    const float* __restrict__ cw1, const float* __restrict__ cb1,
    float* __restrict__ hw_s, unsigned short* __restrict__ hw_dh,
    int N, int E)
{
    int tid = threadIdx.x;
    int n = blockIdx.x * 32 + (tid >> 3);
    if (n >= N) return;
    int g = tid & 7;
    int start = pos[n];
    int end = (n + 1 < N) ? pos[n + 1] : E;

    float acc[16];
    #pragma unroll
    for (int j = 0; j < 16; ++j) acc[j] = 0.0f;

    for (int k = start + g; k < end; k += 8) {
        uint4 u0 = *(const uint4*)(m2h + (size_t)k * 16);
        uint4 u1 = *(const uint4*)(m2h + (size_t)k * 16 + 8);
        float2 f;
        f = unpack2(u0.x); acc[0]  = fmaxf(acc[0],  f.x); acc[1]  = fmaxf(acc[1],  f.y);
        f = unpack2(u0.y); acc[2]  = fmaxf(acc[2],  f.x); acc[3]  = fmaxf(acc[3],  f.y);
        f = unpack2(u0.z); acc[4]  = fmaxf(acc[4],  f.x); acc[5]  = fmaxf(acc[5],  f.y);
        f = unpack2(u0.w); acc[6]  = fmaxf(acc[6],  f.x); acc[7]  = fmaxf(acc[7],  f.y);
        f = unpack2(u1.x); acc[8]  = fmaxf(acc[8],  f.x); acc[9]  = fmaxf(acc[9],  f.y);
        f = unpack2(u1.y); acc[10] = fmaxf(acc[10], f.x); acc[11] = fmaxf(acc[11], f.y);
        f = unpack2(u1.z); acc[12] = fmaxf(acc[12], f.x); acc[13] = fmaxf(acc[13], f.y);
        f = unpack2(u1.w); acc[14] = fmaxf(acc[14], f.x); acc[15] = fmaxf(acc[15], f.y);
    }
    #pragma unroll
    for (int mask = 1; mask < 8; mask <<= 1) {
        #pragma unroll
        for (int j = 0; j < 16; ++j)
            acc[j] = fmaxf(acc[j], __shfl_xor(acc[j], mask, 64));
    }

    int j0 = 2 * g, j1 = 2 * g + 1;
    float hs0 = cb1[j0], hs1 = cb1[j1], hd0 = 0.0f, hd1 = 0.0f;
    #pragma unroll
    for (int k = 0; k < 16; ++k) {
        float ak = acc[k];
        hs0 = fmaf(ak, cw1[k * 16 + j0], hs0);
        hs1 = fmaf(ak, cw1[k * 16 + j1], hs1);
        hd0 = fmaf(ak, cw1[(16 + k) * 16 + j0], hd0);
        hd1 = fmaf(ak, cw1[(16 + k) * 16 + j1], hd1);
    }
    *(float2*)(hw_s + (size_t)n * 16 + j0) = make_float2(hs0, hs1);
    ((unsigned int*)hw_dh)[(size_t)n * 8 + g] = pack2(hd0, hd1);
}

__global__ __launch_bounds__(256) void segmax2_head(
    const _Float16* __restrict__ m2h, const int* __restrict__ pos,
    const float* __restrict__ l1w, const float* __restrict__ l1b,
    const float* __restrict__ l2w, const float* __restrict__ l2b,
    float* __restrict__ out, int N, int E)
{
    int tid = threadIdx.x;
    int n = blockIdx.x * 32 + (tid >> 3);
    if (n >= N) return;
    int g = tid & 7;
    int start = pos[n];
    int end = (n + 1 < N) ? pos[n + 1] : E;

    float acc[16];
    #pragma unroll
    for (int j = 0; j < 16; ++j) acc[j] = 0.0f;

    for (int k = start + g; k < end; k += 8) {
        uint4 u0 = *(const uint4*)(m2h + (size_t)k * 16);
        uint4 u1 = *(const uint4*)(m2h + (size_t)k * 16 + 8);
        float2 f;
        f = unpack2(u0.x); acc[0]  = fmaxf(acc[0],  f.x); acc[1]  = fmaxf(acc[1],  f.y);
        f = unpack2(u0.y); acc[2]  = fmaxf(acc[2],  f.x); acc[3]  = fmaxf(acc[3],  f.y);
        f = unpack2(u0.z); acc[4]  = fmaxf(acc[4],  f.x); acc[5]  = fmaxf(acc[5],  f.y);
        f = unpack2(u0.w); acc[6]  = fmaxf(acc[6],  f.x); acc[7]  = fmaxf(acc[7],  f.y);
        f = unpack2(u1.x); acc[8]  = fmaxf(acc[8],  f.x); acc[9]  = fmaxf(acc[9],  f.y);
        f = unpack2(u1.y); acc[10] = fmaxf(acc[10], f.x); acc[11] = fmaxf(acc[11], f.y);
        f = unpack2(u1.z); acc[12] = fmaxf(acc[12], f.x); acc[13] = fmaxf(acc[13], f.y);
        f = unpack2(u1.w); acc[14] = fmaxf(acc[14], f.x); acc[15] = fmaxf(acc[15], f.y);
    }
    #pragma unroll
    for (int mask = 1; mask < 8; mask <<= 1) {
        #pragma unroll
        for (int j = 0; j < 16; ++j)
            acc[j] = fmaxf(acc[j], __shfl_xor(acc[j], mask, 64));
    }

    float t2[16];
    #pragma unroll
    for (int j = 0; j < 16; ++j) t2[j] = l1b[j];
    #pragma unroll
    for (int kk = 0; kk < 16; ++kk) {
        float ak = acc[kk];
        #pragma unroll
        for (int j = 0; j < 16; ++j) t2[j] = fmaf(ak, l1w[kk * 16 + j], t2[j]);
    }
    float r2 = l2b[0];
    #pragma unroll
    for (int j = 0; j < 16; ++j) r2 = fmaf(fmaxf(t2[j], 0.0f), l2w[j], r2);
    if (g == 0) out[n] = r2;
}

// ===========================================================================
extern "C" void kernel_launch(void* const* d_in, const int* in_sizes, int n_in,
                              void* d_out, int out_size, void* d_ws, size_t ws_size,
                              hipStream_t stream)
{
    const float* x     = (const float*)d_in[0];
    const int*   ei    = (const int*)  d_in[1];
    const float* ea    = (const float*)d_in[2];
    const float* c1_w1 = (const float*)d_in[3];
    const float* c1_b1 = (const float*)d_in[4];
    const float* c1_w2 = (const float*)d_in[5];
    const float* c1_b2 = (const float*)d_in[6];
    const float* c2_w1 = (const float*)d_in[7];
    const float* c2_b1 = (const float*)d_in[8];
    const float* c2_w2 = (const float*)d_in[9];
    const float* c2_b2 = (const float*)d_in[10];
    const float* l1_w  = (const float*)d_in[11];
    const float* l1_b  = (const float*)d_in[12];
    const float* l2_w  = (const float*)d_in[13];
    const float* l2_b  = (const float*)d_in[14];
    float* out = (float*)d_out;

    const int N = in_sizes[0] / 4;   // 100000
    const int E = in_sizes[2] / 8;   // 1600000
    const int nch = (N + CHUNK - 1) / CHUNK;

    const int BLK = 256;
    const int egrid = (E + BLK - 1) / BLK;
    const int ggrid = (N + 31) / 32;
    const int ntiles64 = (E + 63) >> 6;
    int mgrid = (ntiles64 + 15) / 16;        // ~4 tiles per wave
    if (mgrid < 256) mgrid = 256;

    size_t szN16f = (size_t)N * 16 * 4;                 // 6.4 MB
    size_t szN16h = (size_t)N * 16 * 2;                 // 3.2 MB
    size_t szN    = ((size_t)N * 4 + 15) & ~(size_t)15;
    size_t szEh   = ((size_t)E * 2 + 15) & ~(size_t)15; // 3.2 MB
    size_t szE16  = (size_t)E * 16;                     // 25.6 MB (eah)
    size_t szE32  = (size_t)E * 32;                     // 51.2 MB (m2h)
    (void)szE32;

    // ---- workspace (~90 MB; rounds 4/5 proved ws >= ~100 MB) ----
    size_t pos_off  = 0;
    size_t r_off    = pos_off  + szN;
    size_t hws_off  = r_off    + szEh;
    size_t hwdh_off = hws_off  + szN16f;
    size_t eah_off  = hwdh_off + szN16h;
    size_t m2h_off  = eah_off  + szE16;
    // overlays inside m2h (dead before edge_mlp1 writes it):
    size_t deg_off  = m2h_off;
    size_t cs_off   = deg_off  + szN;
    size_t cf_off   = cs_off   + 4096;

    int*            pos  = (int*)  ((char*)d_ws + pos_off);
    unsigned short* r    = (unsigned short*)((char*)d_ws + r_off);
    float*          hw_s = (float*)((char*)d_ws + hws_off);
    unsigned short* hwdh = (unsigned short*)((char*)d_ws + hwdh_off);
    _Float16*       eah  = (_Float16*)((char*)d_ws + eah_off);
    _Float16*       m2h  = (_Float16*)((char*)d_ws + m2h_off);
    int*            deg  = (int*)  ((char*)d_ws + deg_off);
    int*            csum = (int*)  ((char*)d_ws + cs_off);
    int*            coff = (int*)  ((char*)d_ws + cf_off);

    hipMemsetAsync(deg, 0, (size_t)N * 4, stream);
    rank_cvt<<<egrid, BLK, 0, stream>>>(ei, ea, deg, r, eah, E);
    scan_chunk_sums<<<nch, BLK, 0, stream>>>(deg, csum, N);
    scan_chunk_off<<<1, 64, 0, stream>>>(csum, coff, nch);
    scan_within_excl<<<nch, BLK, 0, stream>>>(deg, pos, coff, N);
    edge_mlp1<<<mgrid, BLK, 0, stream>>>(x, ei, eah, pos, r,
                                         c1_w1, c1_b1, c1_w2, c1_b2, m2h, E);
    segmax1_hw<<<ggrid, BLK, 0, stream>>>(m2h, pos, c2_w1, c2_b1,
                                          hw_s, hwdh, N, E);
    edge_mlp2<<<mgrid, BLK, 0, stream>>>(hw_s, hwdh, ei, eah, pos, r,
                                         c2_w1, c2_w2, c2_b2, m2h, E);
    segmax2_head<<<ggrid, BLK, 0, stream>>>(m2h, pos, l1_w, l1_b, l2_w, l2_b,
                                            out, N, E);
}

// Round 8
// 360.531 us; speedup vs baseline: 5.9569x; 1.0401x over previous
//
#include <hip/hip_runtime.h>
#include <hip/hip_fp16.h>

#define CHUNK 1024

typedef _Float16 half8 __attribute__((ext_vector_type(8)));
typedef float floatx4 __attribute__((ext_vector_type(4)));

__device__ __forceinline__ unsigned int pack2(float a, float b) {
    __half2 h = __floats2half2_rn(a, b);
    return *(unsigned int*)&h;
}
__device__ __forceinline__ float2 unpack2(unsigned int u) {
    __half2 h = *(__half2*)&u;
    return __half22float2(h);
}

// ===========================================================================
// rank + fp16-convert fused
// ===========================================================================
__global__ __launch_bounds__(256) void rank_cvt(
    const int* __restrict__ ei, const float* __restrict__ ea,
    int* __restrict__ deg, unsigned short* __restrict__ r,
    _Float16* __restrict__ eah, int E)
{
    int e = blockIdx.x * 256 + threadIdx.x;
    if (e >= E) return;
    r[e] = (unsigned short)atomicAdd(&deg[ei[e]], 1);
    float4 a0 = *(const float4*)(ea + (size_t)e * 8);
    float4 a1 = *(const float4*)(ea + (size_t)e * 8 + 4);
    half8 h;
    h[0] = (_Float16)a0.x; h[1] = (_Float16)a0.y;
    h[2] = (_Float16)a0.z; h[3] = (_Float16)a0.w;
    h[4] = (_Float16)a1.x; h[5] = (_Float16)a1.y;
    h[6] = (_Float16)a1.z; h[7] = (_Float16)a1.w;
    *(half8*)(eah + (size_t)e * 8) = h;
}

__global__ __launch_bounds__(256) void scan_chunk_sums(
    const int* __restrict__ v, int* __restrict__ csum, int N)
{
    __shared__ int s[256];
    int base = blockIdx.x * CHUNK;
    int t = threadIdx.x;
    int acc = 0;
    #pragma unroll
    for (int i = 0; i < CHUNK / 256; ++i) {
        int idx = base + t + i * 256;
        if (idx < N) acc += v[idx];
    }
    s[t] = acc; __syncthreads();
    for (int o = 128; o > 0; o >>= 1) {
        if (t < o) s[t] += s[t + o];
        __syncthreads();
    }
    if (t == 0) csum[blockIdx.x] = s[0];
}

__global__ void scan_chunk_off(
    const int* __restrict__ csum, int* __restrict__ coff, int nch)
{
    if (threadIdx.x == 0 && blockIdx.x == 0) {
        int acc = 0;
        for (int i = 0; i < nch; ++i) { coff[i] = acc; acc += csum[i]; }
    }
}

__global__ __launch_bounds__(256) void scan_within_excl(
    const int* __restrict__ deg, int* __restrict__ pos,
    const int* __restrict__ coff, int N)
{
    __shared__ int s[256];
    int t = threadIdx.x;
    int base = blockIdx.x * CHUNK + t * 4;
    int v0 = 0, v1 = 0, v2 = 0, v3 = 0;
    if (base + 0 < N) v0 = deg[base + 0];
    if (base + 1 < N) v1 = deg[base + 1];
    if (base + 2 < N) v2 = deg[base + 2];
    if (base + 3 < N) v3 = deg[base + 3];
    s[t] = v0 + v1 + v2 + v3;
    __syncthreads();
    for (int o = 1; o < 256; o <<= 1) {
        int add = (t >= o) ? s[t - o] : 0;
        __syncthreads();
        s[t] += add;
        __syncthreads();
    }
    int run = coff[blockIdx.x] + (t > 0 ? s[t - 1] : 0);
    if (base + 0 < N) pos[base + 0] = run; run += v0;
    if (base + 1 < N) pos[base + 1] = run; run += v1;
    if (base + 2 < N) pos[base + 2] = run; run += v2;
    if (base + 3 < N) pos[base + 3] = run;
}

// ===========================================================================
// MFMA edge-MLP: ONE 64-edge macro-tile per wave (4 independent 16x16 MFMA
// tiles). Wave exits after its stores -> scattered-store drain never blocks
// another tile's loads (no loop-carried vmcnt dependency). src/dst sharing
// via __shfl (no LDS stage / barrier).
//   16x16x32 layouts: A[m=lane&15][k=8q+j], B[k=8q+j][n=lane&15],
//   C/D: col=lane&15, row=4q+reg.
// ===========================================================================
__global__ __launch_bounds__(256) void edge_mlp1(
    const float* __restrict__ x,          // [N,4]
    const int*   __restrict__ ei,         // [2,E]
    const _Float16* __restrict__ eah,     // [E,8] fp16
    const int*   __restrict__ pos,
    const unsigned short* __restrict__ r,
    const float* __restrict__ w1, const float* __restrict__ b1,  // 16x16
    const float* __restrict__ w2, const float* __restrict__ b2,  // 16x16
    _Float16* __restrict__ m2h,           // [E,16] CSR-ordered
    int E)
{
    __shared__ _Float16 itm[4][4][16][24];   // [wave][tile][row][ch+pad]
    int tid = threadIdx.x;
    int w = tid >> 6, lane = tid & 63;
    int e16 = lane & 15, q = lane >> 4;
    int ntiles = (E + 63) >> 6;
    int tile = blockIdx.x * 4 + w;
    if (tile >= ntiles) return;
    int ebase = tile << 6;
    int e = ebase + lane;

    // per-lane edge metadata (whole wave, coalesced)
    int s_l = 0, d_l = 0, p_l = 0;
    if (e < E) {
        s_l = ei[e];
        d_l = ei[E + e];
        p_l = pos[s_l] + (int)r[e];
    }

    // weights (wave-uniform scalar loads)
    half8 B1, B2;
    #pragma unroll
    for (int j = 0; j < 8; ++j) { B1[j] = (_Float16)0.f; B2[j] = (_Float16)0.f; }
    if (q < 2) {
        #pragma unroll
        for (int j = 0; j < 8; ++j) {
            B1[j] = (_Float16)w1[(8 * q + j) * 16 + e16];
            B2[j] = (_Float16)w2[(8 * q + j) * 16 + e16];
        }
    }
    float b1c = b1[e16], b2c = b2[e16];

    // phase A: 4 independent A-fragments; src/dst via shfl
    half8 A[4];
    #pragma unroll
    for (int t = 0; t < 4; ++t) {
        int st = __shfl(s_l, 16 * t + e16, 64);
        int dt = __shfl(d_l, 16 * t + e16, 64);
        half8 a;
        #pragma unroll
        for (int j = 0; j < 8; ++j) a[j] = (_Float16)0.f;
        int et = ebase + 16 * t + e16;
        if (q == 0 && et < E) {
            float4 xs = *(const float4*)(x + (size_t)st * 4);
            float4 xd = *(const float4*)(x + (size_t)dt * 4);
            a[0] = (_Float16)xs.x; a[1] = (_Float16)xs.y;
            a[2] = (_Float16)xs.z; a[3] = (_Float16)xs.w;
            a[4] = (_Float16)xd.x; a[5] = (_Float16)xd.y;
            a[6] = (_Float16)xd.z; a[7] = (_Float16)xd.w;
        } else if (q == 1 && et < E) {
            a = *(const half8*)(eah + (size_t)et * 8);
        }
        A[t] = a;
    }

    // layer 1
    floatx4 C[4];
    #pragma unroll
    for (int t = 0; t < 4; ++t) {
        floatx4 c = {b1c, b1c, b1c, b1c};
        C[t] = __builtin_amdgcn_mfma_f32_16x16x32_f16(A[t], B1, c, 0, 0, 0);
    }
    #pragma unroll
    for (int t = 0; t < 4; ++t)
        #pragma unroll
        for (int i = 0; i < 4; ++i)
            itm[w][t][4 * q + i][e16] = (_Float16)fmaxf(C[t][i], 0.0f);
    __builtin_amdgcn_wave_barrier();

    // layer 2
    half8 A2[4];
    #pragma unroll
    for (int t = 0; t < 4; ++t) {
        half8 a;
        #pragma unroll
        for (int j = 0; j < 8; ++j) a[j] = (_Float16)0.f;
        if (q < 2) a = *(const half8*)&itm[w][t][e16][8 * q];
        A2[t] = a;
    }
    __builtin_amdgcn_wave_barrier();
    floatx4 C2[4];
    #pragma unroll
    for (int t = 0; t < 4; ++t) {
        floatx4 c = {b2c, b2c, b2c, b2c};
        C2[t] = __builtin_amdgcn_mfma_f32_16x16x32_f16(A2[t], B2, c, 0, 0, 0);
    }
    #pragma unroll
    for (int t = 0; t < 4; ++t)
        #pragma unroll
        for (int i = 0; i < 4; ++i)
            itm[w][t][4 * q + i][e16] = (_Float16)C2[t][i];
    __builtin_amdgcn_wave_barrier();

    // each lane writes its own edge's full 32 B row to its CSR slot
    if (e < E) {
        half8 lo = *(const half8*)&itm[w][q][e16][0];
        half8 hi = *(const half8*)&itm[w][q][e16][8];
        *(half8*)(m2h + (size_t)p_l * 16)     = lo;
        *(half8*)(m2h + (size_t)p_l * 16 + 8) = hi;
    }
}

__global__ __launch_bounds__(256) void edge_mlp2(
    const float* __restrict__ hw_s,            // [N,16] fp32 (cb1 folded)
    const unsigned short* __restrict__ hw_dh,  // [N,16] fp16
    const int*   __restrict__ ei,
    const _Float16* __restrict__ eah,
    const int*   __restrict__ pos,
    const unsigned short* __restrict__ r,
    const float* __restrict__ w1,              // [40,16] rows 32:40 used
    const float* __restrict__ w2, const float* __restrict__ b2,
    _Float16* __restrict__ m2h, int E)
{
    __shared__ _Float16 itm[4][4][16][24];
    int tid = threadIdx.x;
    int w = tid >> 6, lane = tid & 63;
    int e16 = lane & 15, q = lane >> 4;
    const __half* hwd = (const __half*)hw_dh;
    int ntiles = (E + 63) >> 6;
    int tile = blockIdx.x * 4 + w;
    if (tile >= ntiles) return;
    int ebase = tile << 6;
    int e = ebase + lane;

    int s_l = 0, d_l = 0, p_l = 0;
    if (e < E) {
        s_l = ei[e];
        d_l = ei[E + e];
        p_l = pos[s_l] + (int)r[e];
    }

    half8 B1, B2;
    #pragma unroll
    for (int j = 0; j < 8; ++j) { B1[j] = (_Float16)0.f; B2[j] = (_Float16)0.f; }
    if (q == 0) {
        #pragma unroll
        for (int j = 0; j < 8; ++j)
            B1[j] = (_Float16)w1[(32 + j) * 16 + e16];
    }
    if (q < 2) {
        #pragma unroll
        for (int j = 0; j < 8; ++j)
            B2[j] = (_Float16)w2[(8 * q + j) * 16 + e16];
    }
    float b2c = b2[e16];

    half8 A[4];
    #pragma unroll
    for (int t = 0; t < 4; ++t) {
        half8 a;
        #pragma unroll
        for (int j = 0; j < 8; ++j) a[j] = (_Float16)0.f;
        int et = ebase + 16 * t + e16;
        if (q == 0 && et < E)
            a = *(const half8*)(eah + (size_t)et * 8);
        A[t] = a;
    }

    // C init: hw_s[src[row]][col] + hw_d[dst[row]][col] via shfl'd indices
    floatx4 C[4];
    #pragma unroll
    for (int t = 0; t < 4; ++t) {
        floatx4 c;
        #pragma unroll
        for (int i = 0; i < 4; ++i) {
            int li = 16 * t + 4 * q + i;
            int s = __shfl(s_l, li, 64);
            int d = __shfl(d_l, li, 64);
            int rr = ebase + li;
            float v = 0.0f;
            if (rr < E) {
                v = hw_s[(size_t)s * 16 + e16]
                  + __half2float(hwd[(size_t)d * 16 + e16]);
            }
            c[i] = v;
        }
        C[t] = __builtin_amdgcn_mfma_f32_16x16x32_f16(A[t], B1, c, 0, 0, 0);
    }
    #pragma unroll
    for (int t = 0; t < 4; ++t)
        #pragma unroll
        for (int i = 0; i < 4; ++i)
            itm[w][t][4 * q + i][e16] = (_Float16)fmaxf(C[t][i], 0.0f);
    __builtin_amdgcn_wave_barrier();

    half8 A2[4];
    #pragma unroll
    for (int t = 0; t < 4; ++t) {
        half8 a;
        #pragma unroll
        for (int j = 0; j < 8; ++j) a[j] = (_Float16)0.f;
        if (q < 2) a = *(const half8*)&itm[w][t][e16][8 * q];
        A2[t] = a;
    }
    __builtin_amdgcn_wave_barrier();
    floatx4 C2[4];
    #pragma unroll
    for (int t = 0; t < 4; ++t) {
        floatx4 c = {b2c, b2c, b2c, b2c};
        C2[t] = __builtin_amdgcn_mfma_f32_16x16x32_f16(A2[t], B2, c, 0, 0, 0);
    }
    #pragma unroll
    for (int t = 0; t < 4; ++t)
        #pragma unroll
        for (int i = 0; i < 4; ++i)
            itm[w][t][4 * q + i][e16] = (_Float16)C2[t][i];
    __builtin_amdgcn_wave_barrier();

    if (e < E) {
        half8 lo = *(const half8*)&itm[w][q][e16][0];
        half8 hi = *(const half8*)&itm[w][q][e16][8];
        *(half8*)(m2h + (size_t)p_l * 16)     = lo;
        *(half8*)(m2h + (size_t)p_l * 16 + 8) = hi;
    }
}

// ===========================================================================
// Streaming segment-max kernels (8 lanes/node) + fused epilogues.
// ===========================================================================
__global__ __launch_bounds__(256) void segmax1_hw(
    const _Float16* __restrict__ m2h, const int* __restrict__ pos,
    const float* __restrict__ cw1, const float* __restrict__ cb1,
    float* __restrict__ hw_s, unsigned short* __restrict__ hw_dh,
    int N, int E)
{
    int tid = threadIdx.x;
    int n = blockIdx.x * 32 + (tid >> 3);
    if (n >= N) return;
    int g = tid & 7;
    int start = pos[n];
    int end = (n + 1 < N) ? pos[n + 1] : E;

    float acc[16];
    #pragma unroll
    for (int j = 0; j < 16; ++j) acc[j] = 0.0f;

    for (int k = start + g; k < end; k += 8) {
        uint4 u0 = *(const uint4*)(m2h + (size_t)k * 16);
        uint4 u1 = *(const uint4*)(m2h + (size_t)k * 16 + 8);
        float2 f;
        f = unpack2(u0.x); acc[0]  = fmaxf(acc[0],  f.x); acc[1]  = fmaxf(acc[1],  f.y);
        f = unpack2(u0.y); acc[2]  = fmaxf(acc[2],  f.x); acc[3]  = fmaxf(acc[3],  f.y);
        f = unpack2(u0.z); acc[4]  = fmaxf(acc[4],  f.x); acc[5]  = fmaxf(acc[5],  f.y);
        f = unpack2(u0.w); acc[6]  = fmaxf(acc[6],  f.x); acc[7]  = fmaxf(acc[7],  f.y);
        f = unpack2(u1.x); acc[8]  = fmaxf(acc[8],  f.x); acc[9]  = fmaxf(acc[9],  f.y);
        f = unpack2(u1.y); acc[10] = fmaxf(acc[10], f.x); acc[11] = fmaxf(acc[11], f.y);
        f = unpack2(u1.z); acc[12] = fmaxf(acc[12], f.x); acc[13] = fmaxf(acc[13], f.y);
        f = unpack2(u1.w); acc[14] = fmaxf(acc[14], f.x); acc[15] = fmaxf(acc[15], f.y);
    }
    #pragma unroll
    for (int mask = 1; mask < 8; mask <<= 1) {
        #pragma unroll
        for (int j = 0; j < 16; ++j)
            acc[j] = fmaxf(acc[j], __shfl_xor(acc[j], mask, 64));
    }

    int j0 = 2 * g, j1 = 2 * g + 1;
    float hs0 = cb1[j0], hs1 = cb1[j1], hd0 = 0.0f, hd1 = 0.0f;
    #pragma unroll
    for (int k = 0; k < 16; ++k) {
        float ak = acc[k];
        hs0 = fmaf(ak, cw1[k * 16 + j0], hs0);
        hs1 = fmaf(ak, cw1[k * 16 + j1], hs1);
        hd0 = fmaf(ak, cw1[(16 + k) * 16 + j0], hd0);
        hd1 = fmaf(ak, cw1[(16 + k) * 16 + j1], hd1);
    }
    *(float2*)(hw_s + (size_t)n * 16 + j0) = make_float2(hs0, hs1);
    ((unsigned int*)hw_dh)[(size_t)n * 8 + g] = pack2(hd0, hd1);
}

__global__ __launch_bounds__(256) void segmax2_head(
    const _Float16* __restrict__ m2h, const int* __restrict__ pos,
    const float* __restrict__ l1w, const float* __restrict__ l1b,
    const float* __restrict__ l2w, const float* __restrict__ l2b,
    float* __restrict__ out, int N, int E)
{
    int tid = threadIdx.x;
    int n = blockIdx.x * 32 + (tid >> 3);
    if (n >= N) return;
    int g = tid & 7;
    int start = pos[n];
    int end = (n + 1 < N) ? pos[n + 1] : E;

    float acc[16];
    #pragma unroll
    for (int j = 0; j < 16; ++j) acc[j] = 0.0f;

    for (int k = start + g; k < end; k += 8) {
        uint4 u0 = *(const uint4*)(m2h + (size_t)k * 16);
        uint4 u1 = *(const uint4*)(m2h + (size_t)k * 16 + 8);
        float2 f;
        f = unpack2(u0.x); acc[0]  = fmaxf(acc[0],  f.x); acc[1]  = fmaxf(acc[1],  f.y);
        f = unpack2(u0.y); acc[2]  = fmaxf(acc[2],  f.x); acc[3]  = fmaxf(acc[3],  f.y);
        f = unpack2(u0.z); acc[4]  = fmaxf(acc[4],  f.x); acc[5]  = fmaxf(acc[5],  f.y);
        f = unpack2(u0.w); acc[6]  = fmaxf(acc[6],  f.x); acc[7]  = fmaxf(acc[7],  f.y);
        f = unpack2(u1.x); acc[8]  = fmaxf(acc[8],  f.x); acc[9]  = fmaxf(acc[9],  f.y);
        f = unpack2(u1.y); acc[10] = fmaxf(acc[10], f.x); acc[11] = fmaxf(acc[11], f.y);
        f = unpack2(u1.z); acc[12] = fmaxf(acc[12], f.x); acc[13] = fmaxf(acc[13], f.y);
        f = unpack2(u1.w); acc[14] = fmaxf(acc[14], f.x); acc[15] = fmaxf(acc[15], f.y);
    }
    #pragma unroll
    for (int mask = 1; mask < 8; mask <<= 1) {
        #pragma unroll
        for (int j = 0; j < 16; ++j)
            acc[j] = fmaxf(acc[j], __shfl_xor(acc[j], mask, 64));
    }

    float t2[16];
    #pragma unroll
    for (int j = 0; j < 16; ++j) t2[j] = l1b[j];
    #pragma unroll
    for (int kk = 0; kk < 16; ++kk) {
        float ak = acc[kk];
        #pragma unroll
        for (int j = 0; j < 16; ++j) t2[j] = fmaf(ak, l1w[kk * 16 + j], t2[j]);
    }
    float r2 = l2b[0];
    #pragma unroll
    for (int j = 0; j < 16; ++j) r2 = fmaf(fmaxf(t2[j], 0.0f), l2w[j], r2);
    if (g == 0) out[n] = r2;
}

// ===========================================================================
extern "C" void kernel_launch(void* const* d_in, const int* in_sizes, int n_in,
                              void* d_out, int out_size, void* d_ws, size_t ws_size,
                              hipStream_t stream)
{
    const float* x     = (const float*)d_in[0];
    const int*   ei    = (const int*)  d_in[1];
    const float* ea    = (const float*)d_in[2];
    const float* c1_w1 = (const float*)d_in[3];
    const float* c1_b1 = (const float*)d_in[4];
    const float* c1_w2 = (const float*)d_in[5];
    const float* c1_b2 = (const float*)d_in[6];
    const float* c2_w1 = (const float*)d_in[7];
    const float* c2_b1 = (const float*)d_in[8];
    const float* c2_w2 = (const float*)d_in[9];
    const float* c2_b2 = (const float*)d_in[10];
    const float* l1_w  = (const float*)d_in[11];
    const float* l1_b  = (const float*)d_in[12];
    const float* l2_w  = (const float*)d_in[13];
    const float* l2_b  = (const float*)d_in[14];
    float* out = (float*)d_out;

    const int N = in_sizes[0] / 4;   // 100000
    const int E = in_sizes[2] / 8;   // 1600000
    const int nch = (N + CHUNK - 1) / CHUNK;

    const int BLK = 256;
    const int egrid = (E + BLK - 1) / BLK;
    const int ggrid = (N + 31) / 32;
    const int ntiles64 = (E + 63) >> 6;
    const int mgrid = (ntiles64 + 3) / 4;     // ONE 64-edge tile per wave

    size_t szN16f = (size_t)N * 16 * 4;                 // 6.4 MB
    size_t szN16h = (size_t)N * 16 * 2;                 // 3.2 MB
    size_t szN    = ((size_t)N * 4 + 15) & ~(size_t)15;
    size_t szEh   = ((size_t)E * 2 + 15) & ~(size_t)15; // 3.2 MB
    size_t szE16  = (size_t)E * 16;                     // 25.6 MB (eah)

    size_t pos_off  = 0;
    size_t r_off    = pos_off  + szN;
    size_t hws_off  = r_off    + szEh;
    size_t hwdh_off = hws_off  + szN16f;
    size_t eah_off  = hwdh_off + szN16h;
    size_t m2h_off  = eah_off  + szE16;
    // overlays inside m2h (dead before edge_mlp1 writes it):
    size_t deg_off  = m2h_off;
    size_t cs_off   = deg_off  + szN;
    size_t cf_off   = cs_off   + 4096;

    int*            pos  = (int*)  ((char*)d_ws + pos_off);
    unsigned short* r    = (unsigned short*)((char*)d_ws + r_off);
    float*          hw_s = (float*)((char*)d_ws + hws_off);
    unsigned short* hwdh = (unsigned short*)((char*)d_ws + hwdh_off);
    _Float16*       eah  = (_Float16*)((char*)d_ws + eah_off);
    _Float16*       m2h  = (_Float16*)((char*)d_ws + m2h_off);
    int*            deg  = (int*)  ((char*)d_ws + deg_off);
    int*            csum = (int*)  ((char*)d_ws + cs_off);
    int*            coff = (int*)  ((char*)d_ws + cf_off);

    hipMemsetAsync(deg, 0, (size_t)N * 4, stream);
    rank_cvt<<<egrid, BLK, 0, stream>>>(ei, ea, deg, r, eah, E);
    scan_chunk_sums<<<nch, BLK, 0, stream>>>(deg, csum, N);
    scan_chunk_off<<<1, 64, 0, stream>>>(csum, coff, nch);
    scan_within_excl<<<nch, BLK, 0, stream>>>(deg, pos, coff, N);
    edge_mlp1<<<mgrid, BLK, 0, stream>>>(x, ei, eah, pos, r,
                                         c1_w1, c1_b1, c1_w2, c1_b2, m2h, E);
    segmax1_hw<<<ggrid, BLK, 0, stream>>>(m2h, pos, c2_w1, c2_b1,
                                          hw_s, hwdh, N, E);
    edge_mlp2<<<mgrid, BLK, 0, stream>>>(hw_s, hwdh, ei, eah, pos, r,
                                         c2_w1, c2_w2, c2_b2, m2h, E);
    segmax2_head<<<ggrid, BLK, 0, stream>>>(m2h, pos, l1_w, l1_b, l2_w, l2_b,
                                            out, N, E);
}